// Round 7
// baseline (419.751 us; speedup 1.0000x reference)
//
#include <hip/hip_runtime.h>
#include <hip/hip_bf16.h>

typedef unsigned short u16;
typedef unsigned int   u32;
typedef __bf16 bf16x8 __attribute__((ext_vector_type(8)));
typedef float  f32x4  __attribute__((ext_vector_type(4)));
typedef u16    u16x8  __attribute__((ext_vector_type(8)));
typedef u32    u32x2  __attribute__((ext_vector_type(2)));

#define GAS __attribute__((address_space(1)))
#define LAS __attribute__((address_space(3)))

__device__ __forceinline__ void gload_lds16(const void* g, void* lds) {
  __builtin_amdgcn_global_load_lds((GAS u32*)g, (LAS u32*)lds, 16, 0, 0);
}

__device__ __forceinline__ u16 f2bf(float f) {
  union { float f; u32 u; } v; v.f = f;
  u32 r = v.u + 0x7FFFu + ((v.u >> 16) & 1u);   // round-to-nearest-even
  return (u16)(r >> 16);
}

__device__ __forceinline__ u32 cvtpk_bf16(float lo, float hi) {
  u32 r;
  asm("v_cvt_pk_bf16_f32 %0, %1, %2" : "=v"(r) : "v"(lo), "v"(hi));
  return r;
}

// ---------------- elementwise cast x: f32 -> bf16 (8 elems/thread) ----------------
__global__ __launch_bounds__(256) void cast_x_kernel(const float* __restrict__ x,
                                                     u16* __restrict__ xb) {
  int i = (blockIdx.x * 256 + threadIdx.x) * 8;
  float4 a = *(const float4*)(x + i);
  float4 b = *(const float4*)(x + i + 4);
  u16x8 o;
  o[0] = f2bf(a.x); o[1] = f2bf(a.y); o[2] = f2bf(a.z); o[3] = f2bf(a.w);
  o[4] = f2bf(b.x); o[5] = f2bf(b.y); o[6] = f2bf(b.z); o[7] = f2bf(b.w);
  *(u16x8*)(xb + i) = o;
}

// ---------------- transpose-cast: W[k][n] f32 -> WT[n][k] bf16 (times scale) ------
__global__ __launch_bounds__(256) void transcast(const float* __restrict__ W,
                                                 u16* __restrict__ WT, int dim,
                                                 float scale) {
  __shared__ float t[32][33];
  int tx = threadIdx.x, ty = threadIdx.y;      // 32 x 8
  int c0 = blockIdx.x * 32, r0 = blockIdx.y * 32;
#pragma unroll
  for (int i = 0; i < 4; ++i)
    t[ty + i * 8][tx] = W[(r0 + ty + i * 8) * dim + c0 + tx];
  __syncthreads();
#pragma unroll
  for (int i = 0; i < 4; ++i)
    WT[(c0 + ty + i * 8) * dim + r0 + tx] = f2bf(t[tx][ty + i * 8] * scale);
}

// ---------------- GEMM: C[M][N] = A[M][K] * B^T (B stored [N][K]) ----------------
// 128x128 tile + bijective XCD swizzle (grids are %8 == 0).
template <int OUTF32>
__global__ __launch_bounds__(256) void gemm_bt(
    const u16* __restrict__ A, const u16* __restrict__ B,
    float* __restrict__ Cf, u16* __restrict__ Cb, const float* __restrict__ bias,
    int M, int N, int K, int lda, int ldb, int ldc) {
  __shared__ alignas(16) u16 As[128 * 32];
  __shared__ alignas(16) u16 Bs[128 * 32];
  const int tid = threadIdx.x;
  const int lane = tid & 63, wave = tid >> 6;
  const int wm = wave >> 1, wn = wave & 1;
  const int r15 = lane & 15, g = lane >> 4;

  // XCD swizzle: contiguous tile chunk per XCD
  const int gx = gridDim.x;
  const int nwg = gx * gridDim.y;
  const int orig = blockIdx.y * gx + blockIdx.x;
  const int wg = (orig & 7) * (nwg >> 3) + (orig >> 3);
  const int tm = (wg % gx) * 128, tn = (wg / gx) * 128;

  int aoff[2], boff[2], sbase[2];
#pragma unroll
  for (int i = 0; i < 2; ++i) {
    int c = (i * 4 + wave) * 64 + lane;       // 0..511
    int row = c >> 2;
    int q = (c & 3) ^ ((row >> 1) & 3);
    aoff[i] = (tm + row) * lda + q * 8;
    boff[i] = (tn + row) * ldb + q * 8;
    sbase[i] = (i * 4 + wave) * 1024;
  }
  const int sw = (r15 >> 1) & 3;
  int ard[4], brd[4];
#pragma unroll
  for (int t = 0; t < 4; ++t) {
    ard[t] = (wm * 64 + t * 16 + r15) * 64 + ((g ^ sw) << 4);
    brd[t] = (wn * 64 + t * 16 + r15) * 64 + ((g ^ sw) << 4);
  }

  f32x4 acc[4][4] = {};

  for (int k0 = 0; k0 < K; k0 += 32) {
    __syncthreads();
#pragma unroll
    for (int i = 0; i < 2; ++i) {
      gload_lds16(A + aoff[i] + k0, (char*)As + sbase[i]);
      gload_lds16(B + boff[i] + k0, (char*)Bs + sbase[i]);
    }
    __syncthreads();
    bf16x8 af[4], bfr[4];
#pragma unroll
    for (int t = 0; t < 4; ++t) {
      af[t]  = *(const bf16x8*)((const char*)As + ard[t]);
      bfr[t] = *(const bf16x8*)((const char*)Bs + brd[t]);
    }
#pragma unroll
    for (int mi = 0; mi < 4; ++mi)
#pragma unroll
      for (int ni = 0; ni < 4; ++ni)
        acc[mi][ni] = __builtin_amdgcn_mfma_f32_16x16x32_bf16(af[mi], bfr[ni],
                                                              acc[mi][ni], 0, 0, 0);
  }

#pragma unroll
  for (int mi = 0; mi < 4; ++mi)
#pragma unroll
    for (int ni = 0; ni < 4; ++ni)
#pragma unroll
      for (int r = 0; r < 4; ++r) {
        int m = tm + wm * 64 + mi * 16 + g * 4 + r;
        int n = tn + wn * 64 + ni * 16 + r15;
        float v = acc[mi][ni][r];
        if (OUTF32) Cf[m * ldc + n] = v + bias[n];
        else        Cb[m * ldc + n] = f2bf(v);
      }
}

// ---------------- flash attention: 16x16 MFMA, zero-shuffle PV, hi-occupancy ------
// QK:  [B*S][4096] bf16 rows = {Q[h][d], K_scaled[h][d]}  (K pre-scaled by C2)
// VtG: [2048][4096] bf16 = V^T, row (h*128+d), col (b*2048+s)
// O:   [B*S][2048] bf16
// Block: 4 waves x 16 q-rows = 64 q. KVBLK=32, dbuf K+V (32KB LDS), vmcnt(4).
// Zero-shuffle PV via k-slot placement f(g,j) = 4g + (j&3) + 16*(j>>2): both the
// V^T A-fragment and the P B-fragment use it, so pk words feed the MFMA directly.
__global__ __launch_bounds__(256) void attn_kernel(const u16* __restrict__ QK,
                                                   const u16* __restrict__ VtG,
                                                   u16* __restrict__ O) {
  __shared__ alignas(16) u16 Ks[2][32 * 128];   // 8KB each
  __shared__ alignas(16) u16 Vs[2][128 * 32];   // 8KB each

  const int tid = threadIdx.x, lane = tid & 63, wave = tid >> 6;
  const int r15 = lane & 15, g = lane >> 4;

  // XCD swizzle: cluster q-blocks sharing one head's K/V on the same XCD
  const int orig = (blockIdx.z * 16 + blockIdx.y) * 32 + blockIdx.x;  // 1024 wgs
  const int wg = (orig & 7) * 128 + (orig >> 3);
  const int qb = wg & 31, h = (wg >> 5) & 15, b = wg >> 9;

  const u16* Qp = QK + (size_t)b * 2048 * 4096 + h * 128;
  const u16* Kp = Qp + 2048;
  const u16* Vp = VtG + (size_t)(h * 128) * 4096 + b * 2048;

  // Q fragments: lane owns q = r15 within the wave's 16-row strip
  const int qrow = qb * 64 + wave * 16 + r15;
  bf16x8 qf[4];
#pragma unroll
  for (int kc = 0; kc < 4; ++kc)
    qf[kc] = *(const bf16x8*)(Qp + (size_t)qrow * 4096 + kc * 32 + g * 8);
  asm volatile("s_waitcnt vmcnt(0)" ::: "memory");

  // staging: 512 16B-chunks per tile; wave-uniform LDS base; inverse-swz source
  int koff[2], voff[2];
#pragma unroll
  for (int i = 0; i < 2; ++i) {
    int c = (i * 4 + wave) * 64 + lane;        // 0..511
    int kr = c >> 4, kj = c & 15;              // K: 32 rows x 128 (16 chunks/row)
    koff[i] = kr * 4096 + (kj ^ (kr & 7)) * 8;
    int vr = c >> 2, vj = c & 3;               // V^T: 128 rows x 32 (4 chunks/row)
    voff[i] = vr * 4096 + (vj ^ ((vr >> 1) & 3)) * 8;
  }
  const int sw = r15 & 7;                      // K fragment swizzle (= krow&7)

  f32x4 oacc[8] = {};                          // O^T[d = dt*16+4g+r][q = r15]
  float m = -1e30f, l = 0.f;

  // prologue: stage tile 0
#pragma unroll
  for (int i = 0; i < 2; ++i) {
    gload_lds16(Kp + koff[i], (char*)Ks[0] + (i * 4 + wave) * 1024);
    gload_lds16(Vp + voff[i], (char*)Vs[0] + (i * 4 + wave) * 1024);
  }

  for (int t = 0; t < 64; ++t) {
    const int cur = t & 1;
    if (t < 63) {
      const size_t kv0n = (size_t)(t + 1) * 32;
#pragma unroll
      for (int i = 0; i < 2; ++i) {
        gload_lds16(Kp + kv0n * 4096 + koff[i], (char*)Ks[cur ^ 1] + (i * 4 + wave) * 1024);
        gload_lds16(Vp + kv0n + voff[i], (char*)Vs[cur ^ 1] + (i * 4 + wave) * 1024);
      }
      asm volatile("s_waitcnt vmcnt(4)" ::: "memory");  // drain tile t, keep t+1 in flight
    } else {
      asm volatile("s_waitcnt vmcnt(0)" ::: "memory");
    }
    __builtin_amdgcn_s_barrier();
    __builtin_amdgcn_sched_barrier(0);

    // S^T = K_scaled · Q^T : sacc[tt][r] -> kv = tt*16 + 4g + r, q = r15
    f32x4 sacc[2] = {};
    __builtin_amdgcn_s_setprio(1);
#pragma unroll
    for (int tt = 0; tt < 2; ++tt) {
      const int krow = tt * 16 + r15;
#pragma unroll
      for (int kc = 0; kc < 4; ++kc) {
        bf16x8 kf = *(const bf16x8*)((const char*)Ks[cur] + krow * 256 +
                                     (((kc * 4 + g) ^ sw) << 4));
        sacc[tt] = __builtin_amdgcn_mfma_f32_16x16x32_bf16(kf, qf[kc], sacc[tt], 0, 0, 0);
      }
    }
    __builtin_amdgcn_s_setprio(0);

    // lane-local online softmax over this lane's 8 kv; combine across g-groups
    float mx = fmaxf(fmaxf(sacc[0][0], sacc[0][1]), fmaxf(sacc[0][2], sacc[0][3]));
#pragma unroll
    for (int r = 0; r < 4; ++r) mx = fmaxf(mx, sacc[1][r]);
    mx = fmaxf(mx, __shfl_xor(mx, 16));
    mx = fmaxf(mx, __shfl_xor(mx, 32));

    if (!__all(mx - m <= 8.0f)) {              // defer-max
      float mn = fmaxf(m, mx);
      float alpha = __builtin_amdgcn_exp2f(m - mn);
#pragma unroll
      for (int dt = 0; dt < 8; ++dt) oacc[dt] *= alpha;
      l *= alpha;
      m = mn;
    }

    float rs = 0.f;
    u32 pk[2][2];     // pk[tt][w] = bf16pair(kv = 16tt + 4g + 2w, +1)
#pragma unroll
    for (int tt = 0; tt < 2; ++tt)
#pragma unroll
      for (int w = 0; w < 2; ++w) {
        float p0 = __builtin_amdgcn_exp2f(sacc[tt][2 * w] - m);
        float p1 = __builtin_amdgcn_exp2f(sacc[tt][2 * w + 1] - m);
        rs += p0 + p1;
        pk[tt][w] = cvtpk_bf16(p0, p1);
      }
    rs += __shfl_xor(rs, 16);
    rs += __shfl_xor(rs, 32);
    l += rs;

    // O^T += V^T · P^T  (zero-shuffle B-fragment; A uses the same k-placement)
    union { u32 u4[4]; bf16x8 v; } bfv;
    bfv.u4[0] = pk[0][0]; bfv.u4[1] = pk[0][1];
    bfv.u4[2] = pk[1][0]; bfv.u4[3] = pk[1][1];
    __builtin_amdgcn_s_setprio(1);
#pragma unroll
    for (int dt = 0; dt < 8; ++dt) {
      const int d = dt * 16 + r15;             // A row (m = r15)
      const char* vrow = (const char*)Vs[cur] + d * 64 + (g & 1) * 8;
      const int vsw = (d >> 1) & 3;
      union { u32 u4[4]; bf16x8 v; } af;
      *(u32x2*)&af.u4[0] = *(const u32x2*)(vrow + (((g >> 1) ^ vsw) << 4));
      *(u32x2*)&af.u4[2] = *(const u32x2*)(vrow + ((((g >> 1) + 2) ^ vsw) << 4));
      oacc[dt] = __builtin_amdgcn_mfma_f32_16x16x32_bf16(af.v, bfv.v, oacc[dt], 0, 0, 0);
    }
    __builtin_amdgcn_s_setprio(0);

    __builtin_amdgcn_s_barrier();              // all waves done with buf[cur]
  }

  // epilogue: lane q = qrow; d = dt*16 + 4g + {0..3}; 8B stores
  const float inv = 1.0f / l;
  u16* Ob = O + ((size_t)(b * 2048 + qrow)) * 2048 + h * 128;
#pragma unroll
  for (int dt = 0; dt < 8; ++dt) {
    u32x2 pair;
    pair[0] = cvtpk_bf16(oacc[dt][0] * inv, oacc[dt][1] * inv);
    pair[1] = cvtpk_bf16(oacc[dt][2] * inv, oacc[dt][3] * inv);
    *(u32x2*)(Ob + dt * 16 + 4 * g) = pair;
  }
}

// ---------------- host ----------------
extern "C" void kernel_launch(void* const* d_in, const int* in_sizes, int n_in,
                              void* d_out, int out_size, void* d_ws, size_t ws_size,
                              hipStream_t stream) {
  const float* x  = (const float*)d_in[0];
  const float* Wq = (const float*)d_in[1];
  const float* Wk = (const float*)d_in[2];
  const float* Wv = (const float*)d_in[3];
  const float* Wo = (const float*)d_in[4];
  const float* bo = (const float*)d_in[5];
  float* out = (float*)d_out;

  char* ws = (char*)d_ws;
  u16* xb    = (u16*)ws;                               // 16 MiB (reused as attn O)
  u16* WqkvT = (u16*)(ws + (size_t)16 * 1024 * 1024);  // 24 MiB [6144][2048]
  u16* WoT   = (u16*)(ws + (size_t)40 * 1024 * 1024);  // 8 MiB  [2048][2048]
  u16* QK    = (u16*)(ws + (size_t)48 * 1024 * 1024);  // 32 MiB [4096][4096]
  u16* VtG   = (u16*)(ws + (size_t)80 * 1024 * 1024);  // 16 MiB [2048][4096]
  u16* Oattn = xb;

  const float C2 = 0.12753102f;   // (1/sqrt(128)) * log2(e), folded into Wk

  cast_x_kernel<<<4096, 256, 0, stream>>>(x, xb);
  dim3 tb(32, 8), tg(64, 64);
  transcast<<<tg, tb, 0, stream>>>(Wq, WqkvT, 2048, 1.0f);
  transcast<<<tg, tb, 0, stream>>>(Wk, WqkvT + 2048 * 2048, 2048, C2);
  transcast<<<tg, tb, 0, stream>>>(Wv, WqkvT + 2 * 2048 * 2048, 2048, 1.0f);
  transcast<<<tg, tb, 0, stream>>>(Wo, WoT, 2048, 1.0f);

  // QK = xb @ [Wq|Wk_scaled]   (M=4096, N=4096, K=2048)
  gemm_bt<0><<<dim3(32, 32), 256, 0, stream>>>(xb, WqkvT, nullptr, QK, nullptr,
                                               4096, 4096, 2048, 2048, 2048, 4096);
  // V^T = Wv^T @ x^T    (M=2048, N=4096, K=2048) -> [h*128+d][b*2048+s]
  gemm_bt<0><<<dim3(16, 32), 256, 0, stream>>>(WqkvT + (size_t)4096 * 2048, xb,
                                               nullptr, VtG, nullptr,
                                               2048, 4096, 2048, 2048, 2048, 4096);
  // attention: 64 q-rows per block, 1024 blocks
  attn_kernel<<<dim3(32, 16, 2), 256, 0, stream>>>(QK, VtG, Oattn);
  // out = O @ Wo + bo   (M=4096, N=2048, K=2048), f32 out
  gemm_bt<1><<<dim3(32, 16), 256, 0, stream>>>(Oattn, WoT, out, nullptr, bo,
                                               4096, 2048, 2048, 2048, 2048, 2048);
}

// Round 8
// 351.409 us; speedup vs baseline: 1.1945x; 1.1945x over previous
//
#include <hip/hip_runtime.h>
#include <hip/hip_bf16.h>

typedef unsigned short u16;
typedef unsigned int   u32;
typedef __bf16 bf16x8 __attribute__((ext_vector_type(8)));
typedef float  f32x4  __attribute__((ext_vector_type(4)));
typedef u16    u16x8  __attribute__((ext_vector_type(8)));
typedef u32    u32x2  __attribute__((ext_vector_type(2)));

#define GAS __attribute__((address_space(1)))
#define LAS __attribute__((address_space(3)))

__device__ __forceinline__ void gload_lds16(const void* g, void* lds) {
  __builtin_amdgcn_global_load_lds((GAS u32*)g, (LAS u32*)lds, 16, 0, 0);
}

__device__ __forceinline__ u16 f2bf(float f) {
  union { float f; u32 u; } v; v.f = f;
  u32 r = v.u + 0x7FFFu + ((v.u >> 16) & 1u);   // round-to-nearest-even
  return (u16)(r >> 16);
}

__device__ __forceinline__ u32 cvtpk_bf16(float lo, float hi) {
  u32 r;
  asm("v_cvt_pk_bf16_f32 %0, %1, %2" : "=v"(r) : "v"(lo), "v"(hi));
  return r;
}

// ---------------- elementwise cast x: f32 -> bf16 (8 elems/thread) ----------------
__global__ __launch_bounds__(256) void cast_x_kernel(const float* __restrict__ x,
                                                     u16* __restrict__ xb) {
  int i = (blockIdx.x * 256 + threadIdx.x) * 8;
  float4 a = *(const float4*)(x + i);
  float4 b = *(const float4*)(x + i + 4);
  u16x8 o;
  o[0] = f2bf(a.x); o[1] = f2bf(a.y); o[2] = f2bf(a.z); o[3] = f2bf(a.w);
  o[4] = f2bf(b.x); o[5] = f2bf(b.y); o[6] = f2bf(b.z); o[7] = f2bf(b.w);
  *(u16x8*)(xb + i) = o;
}

// ---------------- transpose-cast: W[k][n] f32 -> WT[n][k] bf16 (times scale) ------
__global__ __launch_bounds__(256) void transcast(const float* __restrict__ W,
                                                 u16* __restrict__ WT, int dim,
                                                 float scale) {
  __shared__ float t[32][33];
  int tx = threadIdx.x, ty = threadIdx.y;      // 32 x 8
  int c0 = blockIdx.x * 32, r0 = blockIdx.y * 32;
#pragma unroll
  for (int i = 0; i < 4; ++i)
    t[ty + i * 8][tx] = W[(r0 + ty + i * 8) * dim + c0 + tx];
  __syncthreads();
#pragma unroll
  for (int i = 0; i < 4; ++i)
    WT[(c0 + ty + i * 8) * dim + r0 + tx] = f2bf(t[tx][ty + i * 8] * scale);
}

// ---------------- GEMM: C[M][N] = A[M][K] * B^T (B stored [N][K]) ----------------
// 128x128 tile + bijective XCD swizzle (grids are %8 == 0).
template <int OUTF32>
__global__ __launch_bounds__(256) void gemm_bt(
    const u16* __restrict__ A, const u16* __restrict__ B,
    float* __restrict__ Cf, u16* __restrict__ Cb, const float* __restrict__ bias,
    int M, int N, int K, int lda, int ldb, int ldc) {
  __shared__ alignas(16) u16 As[128 * 32];
  __shared__ alignas(16) u16 Bs[128 * 32];
  const int tid = threadIdx.x;
  const int lane = tid & 63, wave = tid >> 6;
  const int wm = wave >> 1, wn = wave & 1;
  const int r15 = lane & 15, g = lane >> 4;

  // XCD swizzle: contiguous tile chunk per XCD
  const int gx = gridDim.x;
  const int nwg = gx * gridDim.y;
  const int orig = blockIdx.y * gx + blockIdx.x;
  const int wg = (orig & 7) * (nwg >> 3) + (orig >> 3);
  const int tm = (wg % gx) * 128, tn = (wg / gx) * 128;

  int aoff[2], boff[2], sbase[2];
#pragma unroll
  for (int i = 0; i < 2; ++i) {
    int c = (i * 4 + wave) * 64 + lane;       // 0..511
    int row = c >> 2;
    int q = (c & 3) ^ ((row >> 1) & 3);
    aoff[i] = (tm + row) * lda + q * 8;
    boff[i] = (tn + row) * ldb + q * 8;
    sbase[i] = (i * 4 + wave) * 1024;
  }
  const int sw = (r15 >> 1) & 3;
  int ard[4], brd[4];
#pragma unroll
  for (int t = 0; t < 4; ++t) {
    ard[t] = (wm * 64 + t * 16 + r15) * 64 + ((g ^ sw) << 4);
    brd[t] = (wn * 64 + t * 16 + r15) * 64 + ((g ^ sw) << 4);
  }

  f32x4 acc[4][4] = {};

  for (int k0 = 0; k0 < K; k0 += 32) {
    __syncthreads();
#pragma unroll
    for (int i = 0; i < 2; ++i) {
      gload_lds16(A + aoff[i] + k0, (char*)As + sbase[i]);
      gload_lds16(B + boff[i] + k0, (char*)Bs + sbase[i]);
    }
    __syncthreads();
    bf16x8 af[4], bfr[4];
#pragma unroll
    for (int t = 0; t < 4; ++t) {
      af[t]  = *(const bf16x8*)((const char*)As + ard[t]);
      bfr[t] = *(const bf16x8*)((const char*)Bs + brd[t]);
    }
#pragma unroll
    for (int mi = 0; mi < 4; ++mi)
#pragma unroll
      for (int ni = 0; ni < 4; ++ni)
        acc[mi][ni] = __builtin_amdgcn_mfma_f32_16x16x32_bf16(af[mi], bfr[ni],
                                                              acc[mi][ni], 0, 0, 0);
  }

#pragma unroll
  for (int mi = 0; mi < 4; ++mi)
#pragma unroll
    for (int ni = 0; ni < 4; ++ni)
#pragma unroll
      for (int r = 0; r < 4; ++r) {
        int m = tm + wm * 64 + mi * 16 + g * 4 + r;
        int n = tn + wn * 64 + ni * 16 + r15;
        float v = acc[mi][ni][r];
        if (OUTF32) Cf[m * ldc + n] = v + bias[n];
        else        Cb[m * ldc + n] = f2bf(v);
      }
}

// ---------------- flash attention: 8 waves, KVBLK=64, zero-shuffle PV -------------
// QK:  [B*S][4096] bf16 rows = {Q[h][d], K_scaled[h][d]}  (K pre-scaled by C2)
// VtG: [2048][4096] bf16 = V^T, row (h*128+d), col (b*2048+s)
// O:   [B*S][2048] bf16
// Block: 8 waves x 16 q = 128 q (512 thr). KVBLK=64, dbuf K+V (64KB), vmcnt(4).
// 2 blocks/CU x 8 waves = 16 waves/CU (~50% occ at <=128 VGPR).
// Zero-shuffle PV: k-slot placement f(g,j) = 32kh + 4g + (j&3) + 16*(j>>2) matches
// the 16x16 C-layout's per-lane kv ownership, so pk words feed B directly.
__global__ __launch_bounds__(512, 4) void attn_kernel(const u16* __restrict__ QK,
                                                      const u16* __restrict__ VtG,
                                                      u16* __restrict__ O) {
  __shared__ alignas(16) u16 Ks[2][64 * 128];   // 16KB each
  __shared__ alignas(16) u16 Vs[2][128 * 64];   // 16KB each

  const int tid = threadIdx.x, lane = tid & 63, wave = tid >> 6;
  const int r15 = lane & 15, g = lane >> 4;

  // XCD swizzle: cluster q-blocks sharing one head's K/V on the same XCD
  const int orig = (blockIdx.z * 16 + blockIdx.y) * 16 + blockIdx.x;  // 512 wgs
  const int wg = (orig & 7) * 64 + (orig >> 3);
  const int qb = wg & 15, h = (wg >> 4) & 15, b = wg >> 8;

  const u16* Qp = QK + (size_t)b * 2048 * 4096 + h * 128;
  const u16* Kp = Qp + 2048;
  const u16* Vp = VtG + (size_t)(h * 128) * 4096 + b * 2048;

  // Q fragments: lane owns q = r15 within the wave's 16-row strip
  const int qrow = qb * 128 + wave * 16 + r15;
  bf16x8 qf[4];
#pragma unroll
  for (int kc = 0; kc < 4; ++kc)
    qf[kc] = *(const bf16x8*)(Qp + (size_t)qrow * 4096 + kc * 32 + g * 8);
  asm volatile("s_waitcnt vmcnt(0)" ::: "memory");

  // staging: 1024 16B-chunks per tile over 512 thr (2 each); wave-uniform LDS base
  int koff[2], voff[2];
#pragma unroll
  for (int i = 0; i < 2; ++i) {
    int c = (i * 8 + wave) * 64 + lane;        // 0..1023
    int kr = c >> 4, kj = c & 15;              // K: 64 rows x 128 (16 chunks/row)
    koff[i] = kr * 4096 + (kj ^ (kr & 7)) * 8;
    int vr = c >> 3, vj = c & 7;               // V^T: 128 rows x 64 (8 chunks/row)
    voff[i] = vr * 4096 + (vj ^ (vr & 7)) * 8;
  }
  const int sw = r15 & 7;                      // K fragment swizzle (= krow&7)

  f32x4 oacc[8] = {};                          // O^T[d = dt*16+4g+r][q = r15]
  float m = -1e30f, l = 0.f;

  // prologue: stage tile 0
#pragma unroll
  for (int i = 0; i < 2; ++i) {
    gload_lds16(Kp + koff[i], (char*)Ks[0] + (i * 8 + wave) * 1024);
    gload_lds16(Vp + voff[i], (char*)Vs[0] + (i * 8 + wave) * 1024);
  }

  for (int t = 0; t < 32; ++t) {
    const int cur = t & 1;
    if (t < 31) {
      const size_t kv0n = (size_t)(t + 1) * 64;
#pragma unroll
      for (int i = 0; i < 2; ++i) {
        gload_lds16(Kp + kv0n * 4096 + koff[i], (char*)Ks[cur ^ 1] + (i * 8 + wave) * 1024);
        gload_lds16(Vp + kv0n + voff[i], (char*)Vs[cur ^ 1] + (i * 8 + wave) * 1024);
      }
      asm volatile("s_waitcnt vmcnt(4)" ::: "memory");  // drain tile t, keep t+1 in flight
    } else {
      asm volatile("s_waitcnt vmcnt(0)" ::: "memory");
    }
    __builtin_amdgcn_s_barrier();
    __builtin_amdgcn_sched_barrier(0);

    // S^T = K_scaled · Q^T : sacc[tt][r] -> kv = tt*16 + 4g + r, q = r15
    f32x4 sacc[4] = {};
    __builtin_amdgcn_s_setprio(1);
#pragma unroll
    for (int tt = 0; tt < 4; ++tt) {
      const int krow = tt * 16 + r15;
#pragma unroll
      for (int kc = 0; kc < 4; ++kc) {
        bf16x8 kf = *(const bf16x8*)((const char*)Ks[cur] + krow * 256 +
                                     (((kc * 4 + g) ^ sw) << 4));
        sacc[tt] = __builtin_amdgcn_mfma_f32_16x16x32_bf16(kf, qf[kc], sacc[tt], 0, 0, 0);
      }
    }
    __builtin_amdgcn_s_setprio(0);

    // lane-local online softmax over this lane's 16 kv; combine across g-groups
    float mx = fmaxf(fmaxf(sacc[0][0], sacc[0][1]), fmaxf(sacc[0][2], sacc[0][3]));
#pragma unroll
    for (int tt = 1; tt < 4; ++tt)
#pragma unroll
      for (int r = 0; r < 4; ++r) mx = fmaxf(mx, sacc[tt][r]);
    mx = fmaxf(mx, __shfl_xor(mx, 16));
    mx = fmaxf(mx, __shfl_xor(mx, 32));

    if (!__all(mx - m <= 8.0f)) {              // defer-max
      float mn = fmaxf(m, mx);
      float alpha = __builtin_amdgcn_exp2f(m - mn);
#pragma unroll
      for (int dt = 0; dt < 8; ++dt) oacc[dt] *= alpha;
      l *= alpha;
      m = mn;
    }

    float rs = 0.f;
    u32 pk[4][2];     // pk[tt][w] = bf16pair(kv = 16tt + 4g + 2w, +1)
#pragma unroll
    for (int tt = 0; tt < 4; ++tt)
#pragma unroll
      for (int w = 0; w < 2; ++w) {
        float p0 = __builtin_amdgcn_exp2f(sacc[tt][2 * w] - m);
        float p1 = __builtin_amdgcn_exp2f(sacc[tt][2 * w + 1] - m);
        rs += p0 + p1;
        pk[tt][w] = cvtpk_bf16(p0, p1);
      }
    rs += __shfl_xor(rs, 16);
    rs += __shfl_xor(rs, 32);
    l += rs;

    // O^T += V^T · P^T  (two k-halves; zero-shuffle B; A uses same k-placement)
    __builtin_amdgcn_s_setprio(1);
#pragma unroll
    for (int dt = 0; dt < 8; ++dt) {
      const int d = dt * 16 + r15;             // A row (m = r15)
      const char* vrow = (const char*)Vs[cur] + d * 128 + 8 * (g & 1);
      const int vsw = d & 7;
#pragma unroll
      for (int kh = 0; kh < 2; ++kh) {
        union { u32 u4[4]; bf16x8 v; } af, bfv;
        *(u32x2*)&af.u4[0] = *(const u32x2*)(vrow + (((kh * 4 + (g >> 1)) ^ vsw) << 4));
        *(u32x2*)&af.u4[2] = *(const u32x2*)(vrow + (((kh * 4 + 2 + (g >> 1)) ^ vsw) << 4));
        bfv.u4[0] = pk[2 * kh][0];
        bfv.u4[1] = pk[2 * kh][1];
        bfv.u4[2] = pk[2 * kh + 1][0];
        bfv.u4[3] = pk[2 * kh + 1][1];
        oacc[dt] = __builtin_amdgcn_mfma_f32_16x16x32_bf16(af.v, bfv.v, oacc[dt], 0, 0, 0);
      }
    }
    __builtin_amdgcn_s_setprio(0);

    __builtin_amdgcn_s_barrier();              // all waves done with buf[cur]
  }

  // epilogue: lane q = qrow; d = dt*16 + 4g + {0..3}; 8B stores
  const float inv = 1.0f / l;
  u16* Ob = O + ((size_t)(b * 2048 + qrow)) * 2048 + h * 128;
#pragma unroll
  for (int dt = 0; dt < 8; ++dt) {
    u32x2 pair;
    pair[0] = cvtpk_bf16(oacc[dt][0] * inv, oacc[dt][1] * inv);
    pair[1] = cvtpk_bf16(oacc[dt][2] * inv, oacc[dt][3] * inv);
    *(u32x2*)(Ob + dt * 16 + 4 * g) = pair;
  }
}

// ---------------- host ----------------
extern "C" void kernel_launch(void* const* d_in, const int* in_sizes, int n_in,
                              void* d_out, int out_size, void* d_ws, size_t ws_size,
                              hipStream_t stream) {
  const float* x  = (const float*)d_in[0];
  const float* Wq = (const float*)d_in[1];
  const float* Wk = (const float*)d_in[2];
  const float* Wv = (const float*)d_in[3];
  const float* Wo = (const float*)d_in[4];
  const float* bo = (const float*)d_in[5];
  float* out = (float*)d_out;

  char* ws = (char*)d_ws;
  u16* xb    = (u16*)ws;                               // 16 MiB (reused as attn O)
  u16* WqkvT = (u16*)(ws + (size_t)16 * 1024 * 1024);  // 24 MiB [6144][2048]
  u16* WoT   = (u16*)(ws + (size_t)40 * 1024 * 1024);  // 8 MiB  [2048][2048]
  u16* QK    = (u16*)(ws + (size_t)48 * 1024 * 1024);  // 32 MiB [4096][4096]
  u16* VtG   = (u16*)(ws + (size_t)80 * 1024 * 1024);  // 16 MiB [2048][4096]
  u16* Oattn = xb;

  const float C2 = 0.12753102f;   // (1/sqrt(128)) * log2(e), folded into Wk

  cast_x_kernel<<<4096, 256, 0, stream>>>(x, xb);
  dim3 tb(32, 8), tg(64, 64);
  transcast<<<tg, tb, 0, stream>>>(Wq, WqkvT, 2048, 1.0f);
  transcast<<<tg, tb, 0, stream>>>(Wk, WqkvT + 2048 * 2048, 2048, C2);
  transcast<<<tg, tb, 0, stream>>>(Wv, WqkvT + 2 * 2048 * 2048, 2048, 1.0f);
  transcast<<<tg, tb, 0, stream>>>(Wo, WoT, 2048, 1.0f);

  // QK = xb @ [Wq|Wk_scaled]   (M=4096, N=4096, K=2048)
  gemm_bt<0><<<dim3(32, 32), 256, 0, stream>>>(xb, WqkvT, nullptr, QK, nullptr,
                                               4096, 4096, 2048, 2048, 2048, 4096);
  // V^T = Wv^T @ x^T    (M=2048, N=4096, K=2048) -> [h*128+d][b*2048+s]
  gemm_bt<0><<<dim3(16, 32), 256, 0, stream>>>(WqkvT + (size_t)4096 * 2048, xb,
                                               nullptr, VtG, nullptr,
                                               2048, 4096, 2048, 2048, 2048, 4096);
  // attention: 128 q-rows per block, 512 blocks of 512 threads
  attn_kernel<<<dim3(16, 16, 2), 512, 0, stream>>>(QK, VtG, Oattn);
  // out = O @ Wo + bo   (M=4096, N=2048, K=2048), f32 out
  gemm_bt<1><<<dim3(32, 16), 256, 0, stream>>>(Oattn, WoT, out, nullptr, bo,
                                               4096, 2048, 2048, 2048, 2048, 2048);
}

// Round 9
// 317.496 us; speedup vs baseline: 1.3221x; 1.1068x over previous
//
#include <hip/hip_runtime.h>
#include <hip/hip_bf16.h>

typedef unsigned short u16;
typedef unsigned int   u32;
typedef __bf16 bf16x8 __attribute__((ext_vector_type(8)));
typedef float  f32x4  __attribute__((ext_vector_type(4)));
typedef u16    u16x8  __attribute__((ext_vector_type(8)));
typedef u32    u32x2  __attribute__((ext_vector_type(2)));

#define GAS __attribute__((address_space(1)))
#define LAS __attribute__((address_space(3)))

__device__ __forceinline__ void gload_lds16(const void* g, void* lds) {
  __builtin_amdgcn_global_load_lds((GAS u32*)g, (LAS u32*)lds, 16, 0, 0);
}

__device__ __forceinline__ u16 f2bf(float f) {
  union { float f; u32 u; } v; v.f = f;
  u32 r = v.u + 0x7FFFu + ((v.u >> 16) & 1u);   // round-to-nearest-even
  return (u16)(r >> 16);
}

__device__ __forceinline__ u32 cvtpk_bf16(float lo, float hi) {
  u32 r;
  asm("v_cvt_pk_bf16_f32 %0, %1, %2" : "=v"(r) : "v"(lo), "v"(hi));
  return r;
}

// ---------------- elementwise cast x: f32 -> bf16 (8 elems/thread) ----------------
__global__ __launch_bounds__(256) void cast_x_kernel(const float* __restrict__ x,
                                                     u16* __restrict__ xb) {
  int i = (blockIdx.x * 256 + threadIdx.x) * 8;
  float4 a = *(const float4*)(x + i);
  float4 b = *(const float4*)(x + i + 4);
  u16x8 o;
  o[0] = f2bf(a.x); o[1] = f2bf(a.y); o[2] = f2bf(a.z); o[3] = f2bf(a.w);
  o[4] = f2bf(b.x); o[5] = f2bf(b.y); o[6] = f2bf(b.z); o[7] = f2bf(b.w);
  *(u16x8*)(xb + i) = o;
}

// ---------------- transpose-cast: W[k][n] f32 -> WT[n][k] bf16 (times scale) ------
__global__ __launch_bounds__(256) void transcast(const float* __restrict__ W,
                                                 u16* __restrict__ WT, int dim,
                                                 float scale) {
  __shared__ float t[32][33];
  int tx = threadIdx.x, ty = threadIdx.y;      // 32 x 8
  int c0 = blockIdx.x * 32, r0 = blockIdx.y * 32;
#pragma unroll
  for (int i = 0; i < 4; ++i)
    t[ty + i * 8][tx] = W[(r0 + ty + i * 8) * dim + c0 + tx];
  __syncthreads();
#pragma unroll
  for (int i = 0; i < 4; ++i)
    WT[(c0 + ty + i * 8) * dim + r0 + tx] = f2bf(t[tx][ty + i * 8] * scale);
}

// ---------------- GEMM 256x256, BK=64, 8 waves, counted-vmcnt pipeline ------------
// C[M][N] = A[M][K] * B^T (B stored [N][K]).  LDS [buf][ks][op][256x32] (128 KiB).
// Per K-tile: 2 ks-groups; each: vmcnt(4)+barrier, stage-issue, frag reads (no
// swizzle needed: 4 lanes/row cover full 64B row -> conflict-free), 2x16 MFMA.
// Steady-state vmcnt never drains to 0 (T4); setprio around MFMA clusters (T5).
template <int OUTF32>
__global__ __launch_bounds__(512, 2) void gemm256(
    const u16* __restrict__ A, const u16* __restrict__ B,
    float* __restrict__ Cf, u16* __restrict__ Cb, const float* __restrict__ bias,
    int M, int N, int K, int lda, int ldb, int ldc) {
  __shared__ alignas(16) u16 lds[2][2][2][256 * 32];   // [buf][ks][A|B][8192]

  const int tid = threadIdx.x;                 // 0..511
  const int lane = tid & 63, wave = tid >> 6;
  const int wm = wave >> 2, wn = wave & 3;     // 2 x 4 wave grid
  const int r15 = lane & 15, g = lane >> 4;

  // XCD swizzle (grids are %8 == 0)
  const int gx = gridDim.x;
  const int nwg = gx * gridDim.y;
  const int orig = blockIdx.y * gx + blockIdx.x;
  const int wg = (orig & 7) * (nwg >> 3) + (orig >> 3);
  const int tm = (wg % gx) * 256, tn = (wg / gx) * 256;

  // staging: per (op,ks) sub-tile 1024 chunks of 16B; thread owns chunks
  // c_i = i*512 + wave*64 + lane  (row = c>>2, chunk = c&3)
  int aoff[2], boff[2];
#pragma unroll
  for (int i = 0; i < 2; ++i) {
    int c = i * 512 + wave * 64 + lane;
    int row = c >> 2, ch = c & 3;
    aoff[i] = (tm + row) * lda + ch * 8;
    boff[i] = (tn + row) * ldb + ch * 8;
  }

  auto stage = [&](const u16* P, const int* off, int kofs, void* dst) {
#pragma unroll
    for (int i = 0; i < 2; ++i)
      gload_lds16(P + off[i] + kofs, (char*)dst + (i * 8 + wave) * 1024);
  };

  f32x4 acc[8][4] = {};
  const int NT = K / 64;

  // prologue: tile 0, issue order Aks0, Bks0, Aks1, Bks1 (8 loads/thread)
  stage(A, aoff, 0,  &lds[0][0][0][0]);
  stage(B, boff, 0,  &lds[0][0][1][0]);
  stage(A, aoff, 32, &lds[0][1][0][0]);
  stage(B, boff, 32, &lds[0][1][1][0]);

  for (int t = 0; t < NT; ++t) {
    const int cur = t & 1, nxt = cur ^ 1;
    const int kn = (t + 1 < NT) ? (t + 1) * 64 : 0;   // last tile: dummy restage
#pragma unroll
    for (int ks = 0; ks < 2; ++ks) {
      // wait for this group's operands (oldest 4 loads); keep the rest in flight
      asm volatile("s_waitcnt vmcnt(4)" ::: "memory");
      __builtin_amdgcn_s_barrier();
      __builtin_amdgcn_sched_barrier(0);

      stage(A, aoff, kn + ks * 32, &lds[nxt][ks][0][0]);

      const char* Ab = (const char*)&lds[cur][ks][0][0];
      const char* Bb = (const char*)&lds[cur][ks][1][0];
      bf16x8 bfr[4], af[4];
#pragma unroll
      for (int ni = 0; ni < 4; ++ni)
        bfr[ni] = *(const bf16x8*)(Bb + (wn * 64 + ni * 16 + r15) * 64 + g * 16);
#pragma unroll
      for (int mi = 0; mi < 4; ++mi)
        af[mi] = *(const bf16x8*)(Ab + (wm * 128 + mi * 16 + r15) * 64 + g * 16);

      __builtin_amdgcn_s_setprio(1);
#pragma unroll
      for (int mi = 0; mi < 4; ++mi)
#pragma unroll
        for (int ni = 0; ni < 4; ++ni)
          acc[mi][ni] = __builtin_amdgcn_mfma_f32_16x16x32_bf16(af[mi], bfr[ni],
                                                                acc[mi][ni], 0, 0, 0);
      __builtin_amdgcn_s_setprio(0);

      stage(B, boff, kn + ks * 32, &lds[nxt][ks][1][0]);

#pragma unroll
      for (int mi = 0; mi < 4; ++mi)
        af[mi] = *(const bf16x8*)(Ab + (wm * 128 + (mi + 4) * 16 + r15) * 64 + g * 16);

      __builtin_amdgcn_s_setprio(1);
#pragma unroll
      for (int mi = 0; mi < 4; ++mi)
#pragma unroll
        for (int ni = 0; ni < 4; ++ni)
          acc[mi + 4][ni] = __builtin_amdgcn_mfma_f32_16x16x32_bf16(af[mi], bfr[ni],
                                                                    acc[mi + 4][ni], 0, 0, 0);
      __builtin_amdgcn_s_setprio(0);
    }
  }

  // epilogue
#pragma unroll
  for (int mi = 0; mi < 8; ++mi)
#pragma unroll
    for (int ni = 0; ni < 4; ++ni)
#pragma unroll
      for (int r = 0; r < 4; ++r) {
        int m = tm + wm * 128 + mi * 16 + g * 4 + r;
        int n = tn + wn * 64 + ni * 16 + r15;
        float v = acc[mi][ni][r];
        if (OUTF32) Cf[(size_t)m * ldc + n] = v + bias[n];
        else        Cb[(size_t)m * ldc + n] = f2bf(v);
      }
}

// ---------------- flash attention: 8 waves, KVBLK=64, zero-shuffle PV -------------
// (unchanged from R8: 126 us, occ 40%, proven)
__global__ __launch_bounds__(512, 4) void attn_kernel(const u16* __restrict__ QK,
                                                      const u16* __restrict__ VtG,
                                                      u16* __restrict__ O) {
  __shared__ alignas(16) u16 Ks[2][64 * 128];   // 16KB each
  __shared__ alignas(16) u16 Vs[2][128 * 64];   // 16KB each

  const int tid = threadIdx.x, lane = tid & 63, wave = tid >> 6;
  const int r15 = lane & 15, g = lane >> 4;

  const int orig = (blockIdx.z * 16 + blockIdx.y) * 16 + blockIdx.x;  // 512 wgs
  const int wg = (orig & 7) * 64 + (orig >> 3);
  const int qb = wg & 15, h = (wg >> 4) & 15, b = wg >> 8;

  const u16* Qp = QK + (size_t)b * 2048 * 4096 + h * 128;
  const u16* Kp = Qp + 2048;
  const u16* Vp = VtG + (size_t)(h * 128) * 4096 + b * 2048;

  const int qrow = qb * 128 + wave * 16 + r15;
  bf16x8 qf[4];
#pragma unroll
  for (int kc = 0; kc < 4; ++kc)
    qf[kc] = *(const bf16x8*)(Qp + (size_t)qrow * 4096 + kc * 32 + g * 8);
  asm volatile("s_waitcnt vmcnt(0)" ::: "memory");

  int koff[2], voff[2];
#pragma unroll
  for (int i = 0; i < 2; ++i) {
    int c = (i * 8 + wave) * 64 + lane;        // 0..1023
    int kr = c >> 4, kj = c & 15;
    koff[i] = kr * 4096 + (kj ^ (kr & 7)) * 8;
    int vr = c >> 3, vj = c & 7;
    voff[i] = vr * 4096 + (vj ^ (vr & 7)) * 8;
  }
  const int sw = r15 & 7;

  f32x4 oacc[8] = {};
  float m = -1e30f, l = 0.f;

#pragma unroll
  for (int i = 0; i < 2; ++i) {
    gload_lds16(Kp + koff[i], (char*)Ks[0] + (i * 8 + wave) * 1024);
    gload_lds16(Vp + voff[i], (char*)Vs[0] + (i * 8 + wave) * 1024);
  }

  for (int t = 0; t < 32; ++t) {
    const int cur = t & 1;
    if (t < 31) {
      const size_t kv0n = (size_t)(t + 1) * 64;
#pragma unroll
      for (int i = 0; i < 2; ++i) {
        gload_lds16(Kp + kv0n * 4096 + koff[i], (char*)Ks[cur ^ 1] + (i * 8 + wave) * 1024);
        gload_lds16(Vp + kv0n + voff[i], (char*)Vs[cur ^ 1] + (i * 8 + wave) * 1024);
      }
      asm volatile("s_waitcnt vmcnt(4)" ::: "memory");
    } else {
      asm volatile("s_waitcnt vmcnt(0)" ::: "memory");
    }
    __builtin_amdgcn_s_barrier();
    __builtin_amdgcn_sched_barrier(0);

    f32x4 sacc[4] = {};
    __builtin_amdgcn_s_setprio(1);
#pragma unroll
    for (int tt = 0; tt < 4; ++tt) {
      const int krow = tt * 16 + r15;
#pragma unroll
      for (int kc = 0; kc < 4; ++kc) {
        bf16x8 kf = *(const bf16x8*)((const char*)Ks[cur] + krow * 256 +
                                     (((kc * 4 + g) ^ sw) << 4));
        sacc[tt] = __builtin_amdgcn_mfma_f32_16x16x32_bf16(kf, qf[kc], sacc[tt], 0, 0, 0);
      }
    }
    __builtin_amdgcn_s_setprio(0);

    float mx = fmaxf(fmaxf(sacc[0][0], sacc[0][1]), fmaxf(sacc[0][2], sacc[0][3]));
#pragma unroll
    for (int tt = 1; tt < 4; ++tt)
#pragma unroll
      for (int r = 0; r < 4; ++r) mx = fmaxf(mx, sacc[tt][r]);
    mx = fmaxf(mx, __shfl_xor(mx, 16));
    mx = fmaxf(mx, __shfl_xor(mx, 32));

    if (!__all(mx - m <= 8.0f)) {
      float mn = fmaxf(m, mx);
      float alpha = __builtin_amdgcn_exp2f(m - mn);
#pragma unroll
      for (int dt = 0; dt < 8; ++dt) oacc[dt] *= alpha;
      l *= alpha;
      m = mn;
    }

    float rs = 0.f;
    u32 pk[4][2];
#pragma unroll
    for (int tt = 0; tt < 4; ++tt)
#pragma unroll
      for (int w = 0; w < 2; ++w) {
        float p0 = __builtin_amdgcn_exp2f(sacc[tt][2 * w] - m);
        float p1 = __builtin_amdgcn_exp2f(sacc[tt][2 * w + 1] - m);
        rs += p0 + p1;
        pk[tt][w] = cvtpk_bf16(p0, p1);
      }
    rs += __shfl_xor(rs, 16);
    rs += __shfl_xor(rs, 32);
    l += rs;

    __builtin_amdgcn_s_setprio(1);
#pragma unroll
    for (int dt = 0; dt < 8; ++dt) {
      const int d = dt * 16 + r15;
      const char* vrow = (const char*)Vs[cur] + d * 128 + 8 * (g & 1);
      const int vsw = d & 7;
#pragma unroll
      for (int kh = 0; kh < 2; ++kh) {
        union { u32 u4[4]; bf16x8 v; } af, bfv;
        *(u32x2*)&af.u4[0] = *(const u32x2*)(vrow + (((kh * 4 + (g >> 1)) ^ vsw) << 4));
        *(u32x2*)&af.u4[2] = *(const u32x2*)(vrow + (((kh * 4 + 2 + (g >> 1)) ^ vsw) << 4));
        bfv.u4[0] = pk[2 * kh][0];
        bfv.u4[1] = pk[2 * kh][1];
        bfv.u4[2] = pk[2 * kh + 1][0];
        bfv.u4[3] = pk[2 * kh + 1][1];
        oacc[dt] = __builtin_amdgcn_mfma_f32_16x16x32_bf16(af.v, bfv.v, oacc[dt], 0, 0, 0);
      }
    }
    __builtin_amdgcn_s_setprio(0);

    __builtin_amdgcn_s_barrier();
  }

  const float inv = 1.0f / l;
  u16* Ob = O + ((size_t)(b * 2048 + qrow)) * 2048 + h * 128;
#pragma unroll
  for (int dt = 0; dt < 8; ++dt) {
    u32x2 pair;
    pair[0] = cvtpk_bf16(oacc[dt][0] * inv, oacc[dt][1] * inv);
    pair[1] = cvtpk_bf16(oacc[dt][2] * inv, oacc[dt][3] * inv);
    *(u32x2*)(Ob + dt * 16 + 4 * g) = pair;
  }
}

// ---------------- host ----------------
extern "C" void kernel_launch(void* const* d_in, const int* in_sizes, int n_in,
                              void* d_out, int out_size, void* d_ws, size_t ws_size,
                              hipStream_t stream) {
  const float* x  = (const float*)d_in[0];
  const float* Wq = (const float*)d_in[1];
  const float* Wk = (const float*)d_in[2];
  const float* Wv = (const float*)d_in[3];
  const float* Wo = (const float*)d_in[4];
  const float* bo = (const float*)d_in[5];
  float* out = (float*)d_out;

  char* ws = (char*)d_ws;
  u16* xb    = (u16*)ws;                               // 16 MiB (reused as attn O)
  u16* WqkvT = (u16*)(ws + (size_t)16 * 1024 * 1024);  // 24 MiB [6144][2048]
  u16* WoT   = (u16*)(ws + (size_t)40 * 1024 * 1024);  // 8 MiB  [2048][2048]
  u16* QK    = (u16*)(ws + (size_t)48 * 1024 * 1024);  // 32 MiB [4096][4096]
  u16* VtG   = (u16*)(ws + (size_t)80 * 1024 * 1024);  // 16 MiB [2048][4096]
  u16* Oattn = xb;

  const float C2 = 0.12753102f;   // (1/sqrt(128)) * log2(e), folded into Wk

  cast_x_kernel<<<4096, 256, 0, stream>>>(x, xb);
  dim3 tb(32, 8), tg(64, 64);
  transcast<<<tg, tb, 0, stream>>>(Wq, WqkvT, 2048, 1.0f);
  transcast<<<tg, tb, 0, stream>>>(Wk, WqkvT + 2048 * 2048, 2048, C2);
  transcast<<<tg, tb, 0, stream>>>(Wv, WqkvT + 2 * 2048 * 2048, 2048, 1.0f);
  transcast<<<tg, tb, 0, stream>>>(Wo, WoT, 2048, 1.0f);

  // QK = xb @ [Wq|Wk_scaled]   (M=4096, N=4096, K=2048) -> 16x16 tiles of 256
  gemm256<0><<<dim3(16, 16), 512, 0, stream>>>(xb, WqkvT, nullptr, QK, nullptr,
                                               4096, 4096, 2048, 2048, 2048, 4096);
  // V^T = Wv^T @ x^T    (M=2048, N=4096, K=2048) -> [h*128+d][b*2048+s]
  gemm256<0><<<dim3(8, 16), 512, 0, stream>>>(WqkvT + (size_t)4096 * 2048, xb,
                                              nullptr, VtG, nullptr,
                                              2048, 4096, 2048, 2048, 2048, 4096);
  // attention: 128 q-rows per block, 512 blocks of 512 threads
  attn_kernel<<<dim3(16, 16, 2), 512, 0, stream>>>(QK, VtG, Oattn);
  // out = O @ Wo + bo   (M=4096, N=2048, K=2048), f32 out
  gemm256<1><<<dim3(16, 8), 512, 0, stream>>>(Oattn, WoT, out, nullptr, bo,
                                              4096, 2048, 2048, 2048, 2048, 2048);
}

// Round 10
// 313.388 us; speedup vs baseline: 1.3394x; 1.0131x over previous
//
#include <hip/hip_runtime.h>
#include <hip/hip_bf16.h>

typedef unsigned short u16;
typedef unsigned int   u32;
typedef __bf16 bf16x8 __attribute__((ext_vector_type(8)));
typedef float  f32x4  __attribute__((ext_vector_type(4)));
typedef u16    u16x8  __attribute__((ext_vector_type(8)));
typedef u32    u32x2  __attribute__((ext_vector_type(2)));

#define GAS __attribute__((address_space(1)))
#define LAS __attribute__((address_space(3)))

__device__ __forceinline__ void gload_lds16(const void* g, void* lds) {
  __builtin_amdgcn_global_load_lds((GAS u32*)g, (LAS u32*)lds, 16, 0, 0);
}

__device__ __forceinline__ u16 f2bf(float f) {
  union { float f; u32 u; } v; v.f = f;
  u32 r = v.u + 0x7FFFu + ((v.u >> 16) & 1u);   // round-to-nearest-even
  return (u16)(r >> 16);
}

__device__ __forceinline__ u32 cvtpk_bf16(float lo, float hi) {
  u32 r;
  asm("v_cvt_pk_bf16_f32 %0, %1, %2" : "=v"(r) : "v"(lo), "v"(hi));
  return r;
}

// ---------------- elementwise cast x: f32 -> bf16 (8 elems/thread) ----------------
__global__ __launch_bounds__(256) void cast_x_kernel(const float* __restrict__ x,
                                                     u16* __restrict__ xb) {
  int i = (blockIdx.x * 256 + threadIdx.x) * 8;
  float4 a = *(const float4*)(x + i);
  float4 b = *(const float4*)(x + i + 4);
  u16x8 o;
  o[0] = f2bf(a.x); o[1] = f2bf(a.y); o[2] = f2bf(a.z); o[3] = f2bf(a.w);
  o[4] = f2bf(b.x); o[5] = f2bf(b.y); o[6] = f2bf(b.z); o[7] = f2bf(b.w);
  *(u16x8*)(xb + i) = o;
}

// ---------------- transpose-cast: W[k][n] f32 -> WT[n][k] bf16 (times scale) ------
__global__ __launch_bounds__(256) void transcast(const float* __restrict__ W,
                                                 u16* __restrict__ WT, int dim,
                                                 float scale) {
  __shared__ float t[32][33];
  int tx = threadIdx.x, ty = threadIdx.y;      // 32 x 8
  int c0 = blockIdx.x * 32, r0 = blockIdx.y * 32;
#pragma unroll
  for (int i = 0; i < 4; ++i)
    t[ty + i * 8][tx] = W[(r0 + ty + i * 8) * dim + c0 + tx];
  __syncthreads();
#pragma unroll
  for (int i = 0; i < 4; ++i)
    WT[(c0 + ty + i * 8) * dim + r0 + tx] = f2bf(t[tx][ty + i * 8] * scale);
}

// ---------------- GEMM 256x256, BK=64, 8 waves, counted-vmcnt pipeline ------------
// C[M][N] = A[M][K] * B^T (B stored [N][K]).  LDS [buf][ks][op][256x32] (128 KiB).
// Rows are 64B -> naive reads 8-way conflict; chunk XOR swizzle s(row)=(row>>1)&3
// (pre-swizzled global source + swizzled read; LDS linear for global_load_lds)
// makes fragment reads 2-way (free).  vmcnt never drains to 0 in main loop (T4);
// setprio around MFMA clusters (T5).
template <int OUTF32>
__global__ __launch_bounds__(512, 2) void gemm256(
    const u16* __restrict__ A, const u16* __restrict__ B,
    float* __restrict__ Cf, u16* __restrict__ Cb, const float* __restrict__ bias,
    int M, int N, int K, int lda, int ldb, int ldc) {
  __shared__ alignas(16) u16 lds[2][2][2][256 * 32];   // [buf][ks][A|B][8192]

  const int tid = threadIdx.x;                 // 0..511
  const int lane = tid & 63, wave = tid >> 6;
  const int wm = wave >> 2, wn = wave & 3;     // 2 x 4 wave grid
  const int r15 = lane & 15, g = lane >> 4;

  // XCD swizzle (grids are %8 == 0)
  const int gx = gridDim.x;
  const int nwg = gx * gridDim.y;
  const int orig = blockIdx.y * gx + blockIdx.x;
  const int wg = (orig & 7) * (nwg >> 3) + (orig >> 3);
  const int tm = (wg % gx) * 256, tn = (wg / gx) * 256;

  // staging: per (op,ks) sub-tile 1024 chunks of 16B; LDS byte pos = c*16,
  // i.e. (row = c>>2, chunk = c&3). Source chunk pre-swizzled: ch ^ ((row>>1)&3).
  int aoff[2], boff[2];
#pragma unroll
  for (int i = 0; i < 2; ++i) {
    int c = i * 512 + wave * 64 + lane;
    int row = c >> 2, ch = c & 3;
    int chs = ch ^ ((row >> 1) & 3);
    aoff[i] = (tm + row) * lda + chs * 8;
    boff[i] = (tn + row) * ldb + chs * 8;
  }

  auto stage = [&](const u16* P, const int* off, int kofs, void* dst) {
#pragma unroll
    for (int i = 0; i < 2; ++i)
      gload_lds16(P + off[i] + kofs, (char*)dst + (i * 8 + wave) * 1024);
  };

  f32x4 acc[8][4] = {};
  const int NT = K / 64;
  const int fsw = (r15 >> 1) & 3;              // fragment-read chunk swizzle

  // prologue: tile 0, issue order Aks0, Bks0, Aks1, Bks1 (8 loads/thread)
  stage(A, aoff, 0,  &lds[0][0][0][0]);
  stage(B, boff, 0,  &lds[0][0][1][0]);
  stage(A, aoff, 32, &lds[0][1][0][0]);
  stage(B, boff, 32, &lds[0][1][1][0]);

  for (int t = 0; t < NT; ++t) {
    const int cur = t & 1, nxt = cur ^ 1;
    const int kn = (t + 1 < NT) ? (t + 1) * 64 : 0;   // last tile: dummy restage
#pragma unroll
    for (int ks = 0; ks < 2; ++ks) {
      // wait for this group's operands (oldest 4 loads); keep the rest in flight
      asm volatile("s_waitcnt vmcnt(4)" ::: "memory");
      __builtin_amdgcn_s_barrier();
      __builtin_amdgcn_sched_barrier(0);

      stage(A, aoff, kn + ks * 32, &lds[nxt][ks][0][0]);

      const char* Ab = (const char*)&lds[cur][ks][0][0];
      const char* Bb = (const char*)&lds[cur][ks][1][0];
      bf16x8 bfr[4], af[4];
#pragma unroll
      for (int ni = 0; ni < 4; ++ni)
        bfr[ni] = *(const bf16x8*)(Bb + (wn * 64 + ni * 16 + r15) * 64 +
                                   ((g ^ fsw) << 4));
#pragma unroll
      for (int mi = 0; mi < 4; ++mi)
        af[mi] = *(const bf16x8*)(Ab + (wm * 128 + mi * 16 + r15) * 64 +
                                  ((g ^ fsw) << 4));

      __builtin_amdgcn_s_setprio(1);
#pragma unroll
      for (int mi = 0; mi < 4; ++mi)
#pragma unroll
        for (int ni = 0; ni < 4; ++ni)
          acc[mi][ni] = __builtin_amdgcn_mfma_f32_16x16x32_bf16(af[mi], bfr[ni],
                                                                acc[mi][ni], 0, 0, 0);
      __builtin_amdgcn_s_setprio(0);

      stage(B, boff, kn + ks * 32, &lds[nxt][ks][1][0]);

#pragma unroll
      for (int mi = 0; mi < 4; ++mi)
        af[mi] = *(const bf16x8*)(Ab + (wm * 128 + (mi + 4) * 16 + r15) * 64 +
                                  ((g ^ fsw) << 4));

      __builtin_amdgcn_s_setprio(1);
#pragma unroll
      for (int mi = 0; mi < 4; ++mi)
#pragma unroll
        for (int ni = 0; ni < 4; ++ni)
          acc[mi + 4][ni] = __builtin_amdgcn_mfma_f32_16x16x32_bf16(af[mi], bfr[ni],
                                                                    acc[mi + 4][ni], 0, 0, 0);
      __builtin_amdgcn_s_setprio(0);
    }
  }

  // epilogue
#pragma unroll
  for (int mi = 0; mi < 8; ++mi)
#pragma unroll
    for (int ni = 0; ni < 4; ++ni)
#pragma unroll
      for (int r = 0; r < 4; ++r) {
        int m = tm + wm * 128 + mi * 16 + g * 4 + r;
        int n = tn + wn * 64 + ni * 16 + r15;
        float v = acc[mi][ni][r];
        if (OUTF32) Cf[(size_t)m * ldc + n] = v + bias[n];
        else        Cb[(size_t)m * ldc + n] = f2bf(v);
      }
}

// ---------------- flash attention: 8 waves, KVBLK=64, single-barrier pipeline -----
// QK:  [B*S][4096] bf16 rows = {Q[h][d], K_scaled[h][d]}  (K pre-scaled by C2)
// VtG: [2048][4096] bf16 = V^T, row (h*128+d), col (b*2048+s)
// O:   [B*S][2048] bf16
// T3-min structure: per tile {vmcnt(0); barrier; stage(t+1 -> nxt); compute(cur)}.
// Stage-issue after the barrier makes the buf[nxt] write race-free (all waves'
// reads of iter t-1 were consumed before their barrier); one barrier per tile.
__global__ __launch_bounds__(512, 4) void attn_kernel(const u16* __restrict__ QK,
                                                      const u16* __restrict__ VtG,
                                                      u16* __restrict__ O) {
  __shared__ alignas(16) u16 Ks[2][64 * 128];   // 16KB each
  __shared__ alignas(16) u16 Vs[2][128 * 64];   // 16KB each

  const int tid = threadIdx.x, lane = tid & 63, wave = tid >> 6;
  const int r15 = lane & 15, g = lane >> 4;

  const int orig = (blockIdx.z * 16 + blockIdx.y) * 16 + blockIdx.x;  // 512 wgs
  const int wg = (orig & 7) * 64 + (orig >> 3);
  const int qb = wg & 15, h = (wg >> 4) & 15, b = wg >> 8;

  const u16* Qp = QK + (size_t)b * 2048 * 4096 + h * 128;
  const u16* Kp = Qp + 2048;
  const u16* Vp = VtG + (size_t)(h * 128) * 4096 + b * 2048;

  const int qrow = qb * 128 + wave * 16 + r15;
  bf16x8 qf[4];
#pragma unroll
  for (int kc = 0; kc < 4; ++kc)
    qf[kc] = *(const bf16x8*)(Qp + (size_t)qrow * 4096 + kc * 32 + g * 8);
  asm volatile("s_waitcnt vmcnt(0)" ::: "memory");

  int koff[2], voff[2];
#pragma unroll
  for (int i = 0; i < 2; ++i) {
    int c = (i * 8 + wave) * 64 + lane;        // 0..1023
    int kr = c >> 4, kj = c & 15;
    koff[i] = kr * 4096 + (kj ^ (kr & 7)) * 8;
    int vr = c >> 3, vj = c & 7;
    voff[i] = vr * 4096 + (vj ^ (vr & 7)) * 8;
  }
  const int sw = r15 & 7;

  f32x4 oacc[8] = {};
  float m = -1e30f, l = 0.f;

  // prologue: stage tile 0
#pragma unroll
  for (int i = 0; i < 2; ++i) {
    gload_lds16(Kp + koff[i], (char*)Ks[0] + (i * 8 + wave) * 1024);
    gload_lds16(Vp + voff[i], (char*)Vs[0] + (i * 8 + wave) * 1024);
  }

  for (int t = 0; t < 32; ++t) {
    const int cur = t & 1;
    asm volatile("s_waitcnt vmcnt(0)" ::: "memory");   // tile t's 4 loads landed
    __builtin_amdgcn_s_barrier();                      // all waves: t-1 done, t ready
    __builtin_amdgcn_sched_barrier(0);
    if (t < 31) {                                      // prefetch t+1 into nxt
      const size_t kv0n = (size_t)(t + 1) * 64;
#pragma unroll
      for (int i = 0; i < 2; ++i) {
        gload_lds16(Kp + kv0n * 4096 + koff[i], (char*)Ks[cur ^ 1] + (i * 8 + wave) * 1024);
        gload_lds16(Vp + kv0n + voff[i], (char*)Vs[cur ^ 1] + (i * 8 + wave) * 1024);
      }
      __builtin_amdgcn_sched_barrier(0);
    }

    f32x4 sacc[4] = {};
    __builtin_amdgcn_s_setprio(1);
#pragma unroll
    for (int tt = 0; tt < 4; ++tt) {
      const int krow = tt * 16 + r15;
#pragma unroll
      for (int kc = 0; kc < 4; ++kc) {
        bf16x8 kf = *(const bf16x8*)((const char*)Ks[cur] + krow * 256 +
                                     (((kc * 4 + g) ^ sw) << 4));
        sacc[tt] = __builtin_amdgcn_mfma_f32_16x16x32_bf16(kf, qf[kc], sacc[tt], 0, 0, 0);
      }
    }
    __builtin_amdgcn_s_setprio(0);

    float mx = fmaxf(fmaxf(sacc[0][0], sacc[0][1]), fmaxf(sacc[0][2], sacc[0][3]));
#pragma unroll
    for (int tt = 1; tt < 4; ++tt)
#pragma unroll
      for (int r = 0; r < 4; ++r) mx = fmaxf(mx, sacc[tt][r]);
    mx = fmaxf(mx, __shfl_xor(mx, 16));
    mx = fmaxf(mx, __shfl_xor(mx, 32));

    if (!__all(mx - m <= 8.0f)) {              // defer-max
      float mn = fmaxf(m, mx);
      float alpha = __builtin_amdgcn_exp2f(m - mn);
#pragma unroll
      for (int dt = 0; dt < 8; ++dt) oacc[dt] *= alpha;
      l *= alpha;
      m = mn;
    }

    float rs = 0.f;
    u32 pk[4][2];     // pk[tt][w] = bf16pair(kv = 16tt + 4g + 2w, +1)
#pragma unroll
    for (int tt = 0; tt < 4; ++tt)
#pragma unroll
      for (int w = 0; w < 2; ++w) {
        float p0 = __builtin_amdgcn_exp2f(sacc[tt][2 * w] - m);
        float p1 = __builtin_amdgcn_exp2f(sacc[tt][2 * w + 1] - m);
        rs += p0 + p1;
        pk[tt][w] = cvtpk_bf16(p0, p1);
      }
    rs += __shfl_xor(rs, 16);
    rs += __shfl_xor(rs, 32);
    l += rs;

    // O^T += V^T · P^T (zero-shuffle B; A uses the same k-slot placement)
    __builtin_amdgcn_s_setprio(1);
#pragma unroll
    for (int dt = 0; dt < 8; ++dt) {
      const int d = dt * 16 + r15;
      const char* vrow = (const char*)Vs[cur] + d * 128 + 8 * (g & 1);
      const int vsw = d & 7;
#pragma unroll
      for (int kh = 0; kh < 2; ++kh) {
        union { u32 u4[4]; bf16x8 v; } af, bfv;
        *(u32x2*)&af.u4[0] = *(const u32x2*)(vrow + (((kh * 4 + (g >> 1)) ^ vsw) << 4));
        *(u32x2*)&af.u4[2] = *(const u32x2*)(vrow + (((kh * 4 + 2 + (g >> 1)) ^ vsw) << 4));
        bfv.u4[0] = pk[2 * kh][0];
        bfv.u4[1] = pk[2 * kh][1];
        bfv.u4[2] = pk[2 * kh + 1][0];
        bfv.u4[3] = pk[2 * kh + 1][1];
        oacc[dt] = __builtin_amdgcn_mfma_f32_16x16x32_bf16(af.v, bfv.v, oacc[dt], 0, 0, 0);
      }
    }
    __builtin_amdgcn_s_setprio(0);
  }

  const float inv = 1.0f / l;
  u16* Ob = O + ((size_t)(b * 2048 + qrow)) * 2048 + h * 128;
#pragma unroll
  for (int dt = 0; dt < 8; ++dt) {
    u32x2 pair;
    pair[0] = cvtpk_bf16(oacc[dt][0] * inv, oacc[dt][1] * inv);
    pair[1] = cvtpk_bf16(oacc[dt][2] * inv, oacc[dt][3] * inv);
    *(u32x2*)(Ob + dt * 16 + 4 * g) = pair;
  }
}

// ---------------- host ----------------
extern "C" void kernel_launch(void* const* d_in, const int* in_sizes, int n_in,
                              void* d_out, int out_size, void* d_ws, size_t ws_size,
                              hipStream_t stream) {
  const float* x  = (const float*)d_in[0];
  const float* Wq = (const float*)d_in[1];
  const float* Wk = (const float*)d_in[2];
  const float* Wv = (const float*)d_in[3];
  const float* Wo = (const float*)d_in[4];
  const float* bo = (const float*)d_in[5];
  float* out = (float*)d_out;

  char* ws = (char*)d_ws;
  u16* xb    = (u16*)ws;                               // 16 MiB (reused as attn O)
  u16* WqkvT = (u16*)(ws + (size_t)16 * 1024 * 1024);  // 24 MiB [6144][2048]
  u16* WoT   = (u16*)(ws + (size_t)40 * 1024 * 1024);  // 8 MiB  [2048][2048]
  u16* QK    = (u16*)(ws + (size_t)48 * 1024 * 1024);  // 32 MiB [4096][4096]
  u16* VtG   = (u16*)(ws + (size_t)80 * 1024 * 1024);  // 16 MiB [2048][4096]
  u16* Oattn = xb;

  const float C2 = 0.12753102f;   // (1/sqrt(128)) * log2(e), folded into Wk

  cast_x_kernel<<<4096, 256, 0, stream>>>(x, xb);
  dim3 tb(32, 8), tg(64, 64);
  transcast<<<tg, tb, 0, stream>>>(Wq, WqkvT, 2048, 1.0f);
  transcast<<<tg, tb, 0, stream>>>(Wk, WqkvT + 2048 * 2048, 2048, C2);
  transcast<<<tg, tb, 0, stream>>>(Wv, WqkvT + 2 * 2048 * 2048, 2048, 1.0f);
  transcast<<<tg, tb, 0, stream>>>(Wo, WoT, 2048, 1.0f);

  // QK = xb @ [Wq|Wk_scaled]   (M=4096, N=4096, K=2048) -> 16x16 tiles of 256
  gemm256<0><<<dim3(16, 16), 512, 0, stream>>>(xb, WqkvT, nullptr, QK, nullptr,
                                               4096, 4096, 2048, 2048, 2048, 4096);
  // V^T = Wv^T @ x^T    (M=2048, N=4096, K=2048) -> [h*128+d][b*2048+s]
  gemm256<0><<<dim3(8, 16), 512, 0, stream>>>(WqkvT + (size_t)4096 * 2048, xb,
                                              nullptr, VtG, nullptr,
                                              2048, 4096, 2048, 2048, 2048, 4096);
  // attention: 128 q-rows per block, 512 blocks of 512 threads
  attn_kernel<<<dim3(16, 16, 2), 512, 0, stream>>>(QK, VtG, Oattn);
  // out = O @ Wo + bo   (M=4096, N=2048, K=2048), f32 out
  gemm256<1><<<dim3(16, 8), 512, 0, stream>>>(Oattn, WoT, out, nullptr, bo,
                                              4096, 2048, 2048, 2048, 2048, 2048);
}

// Round 14
// 310.718 us; speedup vs baseline: 1.3509x; 1.0086x over previous
//
#include <hip/hip_runtime.h>
#include <hip/hip_bf16.h>

typedef unsigned short u16;
typedef unsigned int   u32;
typedef __bf16 bf16x8 __attribute__((ext_vector_type(8)));
typedef float  f32x4  __attribute__((ext_vector_type(4)));
typedef u16    u16x8  __attribute__((ext_vector_type(8)));
typedef u32    u32x2  __attribute__((ext_vector_type(2)));

#define GAS __attribute__((address_space(1)))
#define LAS __attribute__((address_space(3)))

__device__ __forceinline__ void gload_lds16(const void* g, void* lds) {
  __builtin_amdgcn_global_load_lds((GAS u32*)g, (LAS u32*)lds, 16, 0, 0);
}

__device__ __forceinline__ u16 f2bf(float f) {
  union { float f; u32 u; } v; v.f = f;
  u32 r = v.u + 0x7FFFu + ((v.u >> 16) & 1u);   // round-to-nearest-even
  return (u16)(r >> 16);
}

__device__ __forceinline__ u32 cvtpk_bf16(float lo, float hi) {
  u32 r;
  asm("v_cvt_pk_bf16_f32 %0, %1, %2" : "=v"(r) : "v"(lo), "v"(hi));
  return r;
}

// ---------------- elementwise cast x: f32 -> bf16 (8 elems/thread) ----------------
__global__ __launch_bounds__(256) void cast_x_kernel(const float* __restrict__ x,
                                                     u16* __restrict__ xb) {
  int i = (blockIdx.x * 256 + threadIdx.x) * 8;
  float4 a = *(const float4*)(x + i);
  float4 b = *(const float4*)(x + i + 4);
  u16x8 o;
  o[0] = f2bf(a.x); o[1] = f2bf(a.y); o[2] = f2bf(a.z); o[3] = f2bf(a.w);
  o[4] = f2bf(b.x); o[5] = f2bf(b.y); o[6] = f2bf(b.z); o[7] = f2bf(b.w);
  *(u16x8*)(xb + i) = o;
}

// ------------- fused transpose-cast: 4x W[k][n] f32 -> WT[n][k] bf16 (x scale) ----
struct TC4 {
  const float* W[4];
  u16* D[4];
  float s[4];
};
__global__ __launch_bounds__(256) void transcast4(TC4 p) {
  __shared__ float t[32][33];
  const int tx = threadIdx.x, ty = threadIdx.y;      // 32 x 8
  const int z = blockIdx.z;
  const float* __restrict__ W = p.W[z];
  u16* __restrict__ WT = p.D[z];
  const float scale = p.s[z];
  const int c0 = blockIdx.x * 32, r0 = blockIdx.y * 32;
#pragma unroll
  for (int i = 0; i < 4; ++i)
    t[ty + i * 8][tx] = W[(r0 + ty + i * 8) * 2048 + c0 + tx];
  __syncthreads();
#pragma unroll
  for (int i = 0; i < 4; ++i)
    WT[(c0 + ty + i * 8) * 2048 + r0 + tx] = f2bf(t[tx][ty + i * 8] * scale);
}

// ---------------- GEMM 256x256, BK=64, 8 waves, counted-vmcnt pipeline ------------
// (exact R10 state — passed; fsw chunk swizzle both-sides)
template <int OUTF32>
__global__ __launch_bounds__(512, 2) void gemm256(
    const u16* __restrict__ A, const u16* __restrict__ B,
    float* __restrict__ Cf, u16* __restrict__ Cb, const float* __restrict__ bias,
    int M, int N, int K, int lda, int ldb, int ldc) {
  __shared__ alignas(16) u16 lds[2][2][2][256 * 32];   // [buf][ks][A|B][8192]

  const int tid = threadIdx.x;                 // 0..511
  const int lane = tid & 63, wave = tid >> 6;
  const int wm = wave >> 2, wn = wave & 3;     // 2 x 4 wave grid
  const int r15 = lane & 15, g = lane >> 4;

  const int gx = gridDim.x;
  const int nwg = gx * gridDim.y;
  const int orig = blockIdx.y * gx + blockIdx.x;
  const int wg = (orig & 7) * (nwg >> 3) + (orig >> 3);
  const int tm = (wg % gx) * 256, tn = (wg / gx) * 256;

  int aoff[2], boff[2];
#pragma unroll
  for (int i = 0; i < 2; ++i) {
    int c = i * 512 + wave * 64 + lane;
    int row = c >> 2, ch = c & 3;
    int chs = ch ^ ((row >> 1) & 3);
    aoff[i] = (tm + row) * lda + chs * 8;
    boff[i] = (tn + row) * ldb + chs * 8;
  }

  auto stage = [&](const u16* P, const int* off, int kofs, void* dst) {
#pragma unroll
    for (int i = 0; i < 2; ++i)
      gload_lds16(P + off[i] + kofs, (char*)dst + (i * 8 + wave) * 1024);
  };

  f32x4 acc[8][4] = {};
  const int NT = K / 64;
  const int fsw = (r15 >> 1) & 3;              // fragment-read chunk swizzle

  stage(A, aoff, 0,  &lds[0][0][0][0]);
  stage(B, boff, 0,  &lds[0][0][1][0]);
  stage(A, aoff, 32, &lds[0][1][0][0]);
  stage(B, boff, 32, &lds[0][1][1][0]);

  for (int t = 0; t < NT; ++t) {
    const int cur = t & 1, nxt = cur ^ 1;
    const int kn = (t + 1 < NT) ? (t + 1) * 64 : 0;   // last tile: dummy restage
#pragma unroll
    for (int ks = 0; ks < 2; ++ks) {
      asm volatile("s_waitcnt vmcnt(4)" ::: "memory");
      __builtin_amdgcn_s_barrier();
      __builtin_amdgcn_sched_barrier(0);

      stage(A, aoff, kn + ks * 32, &lds[nxt][ks][0][0]);

      const char* Ab = (const char*)&lds[cur][ks][0][0];
      const char* Bb = (const char*)&lds[cur][ks][1][0];
      bf16x8 bfr[4], af[4];
#pragma unroll
      for (int ni = 0; ni < 4; ++ni)
        bfr[ni] = *(const bf16x8*)(Bb + (wn * 64 + ni * 16 + r15) * 64 +
                                   ((g ^ fsw) << 4));
#pragma unroll
      for (int mi = 0; mi < 4; ++mi)
        af[mi] = *(const bf16x8*)(Ab + (wm * 128 + mi * 16 + r15) * 64 +
                                  ((g ^ fsw) << 4));

      __builtin_amdgcn_s_setprio(1);
#pragma unroll
      for (int mi = 0; mi < 4; ++mi)
#pragma unroll
        for (int ni = 0; ni < 4; ++ni)
          acc[mi][ni] = __builtin_amdgcn_mfma_f32_16x16x32_bf16(af[mi], bfr[ni],
                                                                acc[mi][ni], 0, 0, 0);
      __builtin_amdgcn_s_setprio(0);

      stage(B, boff, kn + ks * 32, &lds[nxt][ks][1][0]);

#pragma unroll
      for (int mi = 0; mi < 4; ++mi)
        af[mi] = *(const bf16x8*)(Ab + (wm * 128 + (mi + 4) * 16 + r15) * 64 +
                                  ((g ^ fsw) << 4));

      __builtin_amdgcn_s_setprio(1);
#pragma unroll
      for (int mi = 0; mi < 4; ++mi)
#pragma unroll
        for (int ni = 0; ni < 4; ++ni)
          acc[mi + 4][ni] = __builtin_amdgcn_mfma_f32_16x16x32_bf16(af[mi], bfr[ni],
                                                                    acc[mi + 4][ni], 0, 0, 0);
      __builtin_amdgcn_s_setprio(0);
    }
  }

#pragma unroll
  for (int mi = 0; mi < 8; ++mi)
#pragma unroll
    for (int ni = 0; ni < 4; ++ni)
#pragma unroll
      for (int r = 0; r < 4; ++r) {
        int m = tm + wm * 128 + mi * 16 + g * 4 + r;
        int n = tn + wn * 64 + ni * 16 + r15;
        float v = acc[mi][ni][r];
        if (OUTF32) Cf[(size_t)m * ldc + n] = v + bias[n];
        else        Cb[(size_t)m * ldc + n] = f2bf(v);
      }
}

// ---------------- flash attention: 8 waves, KVBLK=64, TWO-barrier pipeline --------
// (exact R8/R9 state — passed twice at 126/125 us. Single-barrier variant reverted:
// it gained ~0 us and is the prime suspect for the R11-R13 intermittent failures.)
// QK:  [B*S][4096] bf16 rows = {Q[h][d], K_scaled[h][d]}  (K pre-scaled by C2)
// VtG: [2048][4096] bf16 = V^T, row (h*128+d), col (b*2048+s)
// O:   [B*S][2048] bf16
__global__ __launch_bounds__(512, 4) void attn_kernel(const u16* __restrict__ QK,
                                                      const u16* __restrict__ VtG,
                                                      u16* __restrict__ O) {
  __shared__ alignas(16) u16 Ks[2][64 * 128];   // 16KB each
  __shared__ alignas(16) u16 Vs[2][128 * 64];   // 16KB each

  const int tid = threadIdx.x, lane = tid & 63, wave = tid >> 6;
  const int r15 = lane & 15, g = lane >> 4;

  const int orig = (blockIdx.z * 16 + blockIdx.y) * 16 + blockIdx.x;  // 512 wgs
  const int wg = (orig & 7) * 64 + (orig >> 3);
  const int qb = wg & 15, h = (wg >> 4) & 15, b = wg >> 8;

  const u16* Qp = QK + (size_t)b * 2048 * 4096 + h * 128;
  const u16* Kp = Qp + 2048;
  const u16* Vp = VtG + (size_t)(h * 128) * 4096 + b * 2048;

  const int qrow = qb * 128 + wave * 16 + r15;
  bf16x8 qf[4];
#pragma unroll
  for (int kc = 0; kc < 4; ++kc)
    qf[kc] = *(const bf16x8*)(Qp + (size_t)qrow * 4096 + kc * 32 + g * 8);
  asm volatile("s_waitcnt vmcnt(0)" ::: "memory");

  int koff[2], voff[2];
#pragma unroll
  for (int i = 0; i < 2; ++i) {
    int c = (i * 8 + wave) * 64 + lane;        // 0..1023
    int kr = c >> 4, kj = c & 15;
    koff[i] = kr * 4096 + (kj ^ (kr & 7)) * 8;
    int vr = c >> 3, vj = c & 7;
    voff[i] = vr * 4096 + (vj ^ (vr & 7)) * 8;
  }
  const int sw = r15 & 7;

  f32x4 oacc[8] = {};
  float m = -1e30f, l = 0.f;

  // prologue: stage tile 0
#pragma unroll
  for (int i = 0; i < 2; ++i) {
    gload_lds16(Kp + koff[i], (char*)Ks[0] + (i * 8 + wave) * 1024);
    gload_lds16(Vp + voff[i], (char*)Vs[0] + (i * 8 + wave) * 1024);
  }

  for (int t = 0; t < 32; ++t) {
    const int cur = t & 1;
    if (t < 31) {
      const size_t kv0n = (size_t)(t + 1) * 64;
#pragma unroll
      for (int i = 0; i < 2; ++i) {
        gload_lds16(Kp + kv0n * 4096 + koff[i], (char*)Ks[cur ^ 1] + (i * 8 + wave) * 1024);
        gload_lds16(Vp + kv0n + voff[i], (char*)Vs[cur ^ 1] + (i * 8 + wave) * 1024);
      }
      asm volatile("s_waitcnt vmcnt(4)" ::: "memory");  // drain tile t, keep t+1 in flight
    } else {
      asm volatile("s_waitcnt vmcnt(0)" ::: "memory");
    }
    __builtin_amdgcn_s_barrier();
    __builtin_amdgcn_sched_barrier(0);

    f32x4 sacc[4] = {};
    __builtin_amdgcn_s_setprio(1);
#pragma unroll
    for (int tt = 0; tt < 4; ++tt) {
      const int krow = tt * 16 + r15;
#pragma unroll
      for (int kc = 0; kc < 4; ++kc) {
        bf16x8 kf = *(const bf16x8*)((const char*)Ks[cur] + krow * 256 +
                                     (((kc * 4 + g) ^ sw) << 4));
        sacc[tt] = __builtin_amdgcn_mfma_f32_16x16x32_bf16(kf, qf[kc], sacc[tt], 0, 0, 0);
      }
    }
    __builtin_amdgcn_s_setprio(0);

    float mx = fmaxf(fmaxf(sacc[0][0], sacc[0][1]), fmaxf(sacc[0][2], sacc[0][3]));
#pragma unroll
    for (int tt = 1; tt < 4; ++tt)
#pragma unroll
      for (int r = 0; r < 4; ++r) mx = fmaxf(mx, sacc[tt][r]);
    mx = fmaxf(mx, __shfl_xor(mx, 16));
    mx = fmaxf(mx, __shfl_xor(mx, 32));

    if (!__all(mx - m <= 8.0f)) {              // defer-max
      float mn = fmaxf(m, mx);
      float alpha = __builtin_amdgcn_exp2f(m - mn);
#pragma unroll
      for (int dt = 0; dt < 8; ++dt) oacc[dt] *= alpha;
      l *= alpha;
      m = mn;
    }

    float rs = 0.f;
    u32 pk[4][2];     // pk[tt][w] = bf16pair(kv = 16tt + 4g + 2w, +1)
#pragma unroll
    for (int tt = 0; tt < 4; ++tt)
#pragma unroll
      for (int w = 0; w < 2; ++w) {
        float p0 = __builtin_amdgcn_exp2f(sacc[tt][2 * w] - m);
        float p1 = __builtin_amdgcn_exp2f(sacc[tt][2 * w + 1] - m);
        rs += p0 + p1;
        pk[tt][w] = cvtpk_bf16(p0, p1);
      }
    rs += __shfl_xor(rs, 16);
    rs += __shfl_xor(rs, 32);
    l += rs;

    // O^T += V^T · P^T (zero-shuffle B; A uses the same k-slot placement)
    __builtin_amdgcn_s_setprio(1);
#pragma unroll
    for (int dt = 0; dt < 8; ++dt) {
      const int d = dt * 16 + r15;
      const char* vrow = (const char*)Vs[cur] + d * 128 + 8 * (g & 1);
      const int vsw = d & 7;
#pragma unroll
      for (int kh = 0; kh < 2; ++kh) {
        union { u32 u4[4]; bf16x8 v; } af, bfv;
        *(u32x2*)&af.u4[0] = *(const u32x2*)(vrow + (((kh * 4 + (g >> 1)) ^ vsw) << 4));
        *(u32x2*)&af.u4[2] = *(const u32x2*)(vrow + (((kh * 4 + 2 + (g >> 1)) ^ vsw) << 4));
        bfv.u4[0] = pk[2 * kh][0];
        bfv.u4[1] = pk[2 * kh][1];
        bfv.u4[2] = pk[2 * kh + 1][0];
        bfv.u4[3] = pk[2 * kh + 1][1];
        oacc[dt] = __builtin_amdgcn_mfma_f32_16x16x32_bf16(af.v, bfv.v, oacc[dt], 0, 0, 0);
      }
    }
    __builtin_amdgcn_s_setprio(0);

    __builtin_amdgcn_s_barrier();              // all waves done with buf[cur]
  }

  const float inv = 1.0f / l;
  u16* Ob = O + ((size_t)(b * 2048 + qrow)) * 2048 + h * 128;
#pragma unroll
  for (int dt = 0; dt < 8; ++dt) {
    u32x2 pair;
    pair[0] = cvtpk_bf16(oacc[dt][0] * inv, oacc[dt][1] * inv);
    pair[1] = cvtpk_bf16(oacc[dt][2] * inv, oacc[dt][3] * inv);
    *(u32x2*)(Ob + dt * 16 + 4 * g) = pair;
  }
}

// ---------------- host ----------------
extern "C" void kernel_launch(void* const* d_in, const int* in_sizes, int n_in,
                              void* d_out, int out_size, void* d_ws, size_t ws_size,
                              hipStream_t stream) {
  const float* x  = (const float*)d_in[0];
  const float* Wq = (const float*)d_in[1];
  const float* Wk = (const float*)d_in[2];
  const float* Wv = (const float*)d_in[3];
  const float* Wo = (const float*)d_in[4];
  const float* bo = (const float*)d_in[5];
  float* out = (float*)d_out;

  char* ws = (char*)d_ws;
  u16* xb    = (u16*)ws;                               // 16 MiB (reused as attn O)
  u16* WqkvT = (u16*)(ws + (size_t)16 * 1024 * 1024);  // 24 MiB [6144][2048]
  u16* WoT   = (u16*)(ws + (size_t)40 * 1024 * 1024);  // 8 MiB  [2048][2048]
  u16* QK    = (u16*)(ws + (size_t)48 * 1024 * 1024);  // 32 MiB [4096][4096]
  u16* VtG   = (u16*)(ws + (size_t)80 * 1024 * 1024);  // 16 MiB [2048][4096]
  u16* Oattn = xb;

  const float C2 = 0.12753102f;   // (1/sqrt(128)) * log2(e), folded into Wk

  cast_x_kernel<<<4096, 256, 0, stream>>>(x, xb);

  TC4 p;
  p.W[0] = Wq; p.W[1] = Wk; p.W[2] = Wv; p.W[3] = Wo;
  p.D[0] = WqkvT;
  p.D[1] = WqkvT + (size_t)2048 * 2048;
  p.D[2] = WqkvT + (size_t)4096 * 2048;
  p.D[3] = WoT;
  p.s[0] = 1.0f; p.s[1] = C2; p.s[2] = 1.0f; p.s[3] = 1.0f;
  transcast4<<<dim3(64, 64, 4), dim3(32, 8), 0, stream>>>(p);

  // QK = xb @ [Wq|Wk_scaled]   (M=4096, N=4096, K=2048) -> 16x16 tiles of 256
  gemm256<0><<<dim3(16, 16), 512, 0, stream>>>(xb, WqkvT, nullptr, QK, nullptr,
                                               4096, 4096, 2048, 2048, 2048, 4096);
  // V^T = Wv^T @ x^T    (M=2048, N=4096, K=2048) -> [h*128+d][b*2048+s]
  gemm256<0><<<dim3(8, 16), 512, 0, stream>>>(WqkvT + (size_t)4096 * 2048, xb,
                                              nullptr, VtG, nullptr,
                                              2048, 4096, 2048, 2048, 2048, 4096);
  // attention: 128 q-rows per block, 512 blocks of 512 threads
  attn_kernel<<<dim3(16, 16, 2), 512, 0, stream>>>(QK, VtG, Oattn);
  // out = O @ Wo + bo   (M=4096, N=2048, K=2048), f32 out
  gemm256<1><<<dim3(16, 8), 512, 0, stream>>>(Oattn, WoT, out, nullptr, bo,
                                              4096, 2048, 2048, 2048, 2048, 2048);
}

// Round 15
// 287.018 us; speedup vs baseline: 1.4625x; 1.0826x over previous
//
#include <hip/hip_runtime.h>
#include <hip/hip_bf16.h>

typedef unsigned short u16;
typedef unsigned int   u32;
typedef __bf16 bf16x8 __attribute__((ext_vector_type(8)));
typedef float  f32x4  __attribute__((ext_vector_type(4)));
typedef u16    u16x8  __attribute__((ext_vector_type(8)));
typedef u32    u32x2  __attribute__((ext_vector_type(2)));

#define GAS __attribute__((address_space(1)))
#define LAS __attribute__((address_space(3)))

__device__ __forceinline__ void gload_lds16(const void* g, void* lds) {
  __builtin_amdgcn_global_load_lds((GAS u32*)g, (LAS u32*)lds, 16, 0, 0);
}

__device__ __forceinline__ u16 f2bf(float f) {
  union { float f; u32 u; } v; v.f = f;
  u32 r = v.u + 0x7FFFu + ((v.u >> 16) & 1u);   // round-to-nearest-even
  return (u16)(r >> 16);
}

__device__ __forceinline__ u32 cvtpk_bf16(float lo, float hi) {
  u32 r;
  asm("v_cvt_pk_bf16_f32 %0, %1, %2" : "=v"(r) : "v"(lo), "v"(hi));
  return r;
}

template <int N> __device__ __forceinline__ void wait_vmcnt() {
  if constexpr (N == 3)      asm volatile("s_waitcnt vmcnt(3)" ::: "memory");
  else if constexpr (N == 4) asm volatile("s_waitcnt vmcnt(4)" ::: "memory");
  else                       asm volatile("s_waitcnt vmcnt(0)" ::: "memory");
}

// ---------------- elementwise cast x: f32 -> bf16 (8 elems/thread) ----------------
__global__ __launch_bounds__(256) void cast_x_kernel(const float* __restrict__ x,
                                                     u16* __restrict__ xb) {
  int i = (blockIdx.x * 256 + threadIdx.x) * 8;
  float4 a = *(const float4*)(x + i);
  float4 b = *(const float4*)(x + i + 4);
  u16x8 o;
  o[0] = f2bf(a.x); o[1] = f2bf(a.y); o[2] = f2bf(a.z); o[3] = f2bf(a.w);
  o[4] = f2bf(b.x); o[5] = f2bf(b.y); o[6] = f2bf(b.z); o[7] = f2bf(b.w);
  *(u16x8*)(xb + i) = o;
}

// ------------- fused transpose-cast: 4x W[k][n] f32 -> WT[n][k] bf16 (x scale) ----
struct TC4 {
  const float* W[4];
  u16* D[4];
  float s[4];
};
__global__ __launch_bounds__(256) void transcast4(TC4 p) {
  __shared__ float t[32][33];
  const int tx = threadIdx.x, ty = threadIdx.y;      // 32 x 8
  const int z = blockIdx.z;
  const float* __restrict__ W = p.W[z];
  u16* __restrict__ WT = p.D[z];
  const float scale = p.s[z];
  const int c0 = blockIdx.x * 32, r0 = blockIdx.y * 32;
#pragma unroll
  for (int i = 0; i < 4; ++i)
    t[ty + i * 8][tx] = W[(r0 + ty + i * 8) * 2048 + c0 + tx];
  __syncthreads();
#pragma unroll
  for (int i = 0; i < 4; ++i)
    WT[(c0 + ty + i * 8) * 2048 + r0 + tx] = f2bf(t[tx][ty + i * 8] * scale);
}

// ---------------- GEMM BMxBN, BK=64, 8 waves, counted-vmcnt pipeline --------------
// Generalized geometry of the R10/R14-proven 256x256 kernel. C = A * B^T.
// LDS [buf][ks][A(BM x 32) | B(BN x 32)]; chunk swizzle ch^((row>>1)&3) both-sides;
// steady-state vmcnt(cA+cB) never drains to 0 (T4); setprio on MFMA clusters (T5).
// BM=BN=256: 128KB LDS (QK GEMM, identical to R14). 128x256 / 256x128: 96KB,
// grid 16x16=256 wgs -> FULL machine for the Vt and Wo GEMMs (was 128 wgs = half).
template <int OUTF32, int BM, int BN, int WM, int WN>
__global__ __launch_bounds__(512, 2) void gemm256(
    const u16* __restrict__ A, const u16* __restrict__ B,
    float* __restrict__ Cf, u16* __restrict__ Cb, const float* __restrict__ bias,
    int M, int N, int K, int lda, int ldb, int ldc) {
  constexpr int PM = BM / WM, PN = BN / WN;    // per-wave output
  constexpr int MI = PM / 16, NI = PN / 16;    // acc tile counts
  constexpr int CA = BM / 128, CB = BN / 128;  // staging chunks per thread
  __shared__ alignas(16) u16 lds[2][2][(BM + BN) * 32];

  const int tid = threadIdx.x;                 // 0..511
  const int lane = tid & 63, wave = tid >> 6;
  const int wm = wave / WN, wn = wave % WN;
  const int r15 = lane & 15, g = lane >> 4;

  const int gx = gridDim.x;
  const int nwg = gx * gridDim.y;
  const int orig = blockIdx.y * gx + blockIdx.x;
  const int wg = (orig & 7) * (nwg >> 3) + (orig >> 3);
  const int tm = (wg % gx) * BM, tn = (wg / gx) * BN;

  int aoff[CA], boff[CB];
#pragma unroll
  for (int i = 0; i < CA; ++i) {
    int c = i * 512 + tid, row = c >> 2, ch = c & 3;
    aoff[i] = (tm + row) * lda + (ch ^ ((row >> 1) & 3)) * 8;
  }
#pragma unroll
  for (int i = 0; i < CB; ++i) {
    int c = i * 512 + tid, row = c >> 2, ch = c & 3;
    boff[i] = (tn + row) * ldb + (ch ^ ((row >> 1) & 3)) * 8;
  }

  auto stageA = [&](int kofs, int buf, int ks) {
#pragma unroll
    for (int i = 0; i < CA; ++i)
      gload_lds16(A + aoff[i] + kofs,
                  (char*)&lds[buf][ks][0] + (i * 8 + wave) * 1024);
  };
  auto stageB = [&](int kofs, int buf, int ks) {
#pragma unroll
    for (int i = 0; i < CB; ++i)
      gload_lds16(B + boff[i] + kofs,
                  (char*)&lds[buf][ks][BM * 32] + (i * 8 + wave) * 1024);
  };

  f32x4 acc[MI][NI] = {};
  const int NT = K / 64;
  const int fsw = (r15 >> 1) & 3;              // fragment-read chunk swizzle

  stageA(0, 0, 0);  stageB(0, 0, 0);
  stageA(32, 0, 1); stageB(32, 0, 1);

  for (int t = 0; t < NT; ++t) {
    const int cur = t & 1, nxt = cur ^ 1;
    const int kn = (t + 1 < NT) ? (t + 1) * 64 : 0;   // last tile: dummy restage
#pragma unroll
    for (int ks = 0; ks < 2; ++ks) {
      wait_vmcnt<CA + CB>();                   // drain this group's operands only
      __builtin_amdgcn_s_barrier();
      __builtin_amdgcn_sched_barrier(0);

      stageA(kn + ks * 32, nxt, ks);

      const char* Ab = (const char*)&lds[cur][ks][0];
      const char* Bb = (const char*)&lds[cur][ks][BM * 32];
      bf16x8 bfr[NI], af[MI / 2];
#pragma unroll
      for (int ni = 0; ni < NI; ++ni)
        bfr[ni] = *(const bf16x8*)(Bb + (wn * PN + ni * 16 + r15) * 64 +
                                   ((g ^ fsw) << 4));
#pragma unroll
      for (int mi = 0; mi < MI / 2; ++mi)
        af[mi] = *(const bf16x8*)(Ab + (wm * PM + mi * 16 + r15) * 64 +
                                  ((g ^ fsw) << 4));

      __builtin_amdgcn_s_setprio(1);
#pragma unroll
      for (int mi = 0; mi < MI / 2; ++mi)
#pragma unroll
        for (int ni = 0; ni < NI; ++ni)
          acc[mi][ni] = __builtin_amdgcn_mfma_f32_16x16x32_bf16(af[mi], bfr[ni],
                                                                acc[mi][ni], 0, 0, 0);
      __builtin_amdgcn_s_setprio(0);

      stageB(kn + ks * 32, nxt, ks);

#pragma unroll
      for (int mi = 0; mi < MI / 2; ++mi)
        af[mi] = *(const bf16x8*)(Ab + (wm * PM + (mi + MI / 2) * 16 + r15) * 64 +
                                  ((g ^ fsw) << 4));

      __builtin_amdgcn_s_setprio(1);
#pragma unroll
      for (int mi = 0; mi < MI / 2; ++mi)
#pragma unroll
        for (int ni = 0; ni < NI; ++ni)
          acc[mi + MI / 2][ni] = __builtin_amdgcn_mfma_f32_16x16x32_bf16(
              af[mi], bfr[ni], acc[mi + MI / 2][ni], 0, 0, 0);
      __builtin_amdgcn_s_setprio(0);
    }
  }

  // epilogue
#pragma unroll
  for (int mi = 0; mi < MI; ++mi)
#pragma unroll
    for (int ni = 0; ni < NI; ++ni)
#pragma unroll
      for (int r = 0; r < 4; ++r) {
        int m = tm + wm * PM + mi * 16 + g * 4 + r;
        int n = tn + wn * PN + ni * 16 + r15;
        float v = acc[mi][ni][r];
        if (OUTF32) Cf[(size_t)m * ldc + n] = v + bias[n];
        else        Cb[(size_t)m * ldc + n] = f2bf(v);
      }
}

// ---------------- flash attention: 8 waves, KVBLK=64, TWO-barrier pipeline --------
// (exact R8/R9/R14 state — passed three times at ~126 us. DO NOT TOUCH.)
// QK:  [B*S][4096] bf16 rows = {Q[h][d], K_scaled[h][d]}  (K pre-scaled by C2)
// VtG: [2048][4096] bf16 = V^T, row (h*128+d), col (b*2048+s)
// O:   [B*S][2048] bf16
__global__ __launch_bounds__(512, 4) void attn_kernel(const u16* __restrict__ QK,
                                                      const u16* __restrict__ VtG,
                                                      u16* __restrict__ O) {
  __shared__ alignas(16) u16 Ks[2][64 * 128];   // 16KB each
  __shared__ alignas(16) u16 Vs[2][128 * 64];   // 16KB each

  const int tid = threadIdx.x, lane = tid & 63, wave = tid >> 6;
  const int r15 = lane & 15, g = lane >> 4;

  const int orig = (blockIdx.z * 16 + blockIdx.y) * 16 + blockIdx.x;  // 512 wgs
  const int wg = (orig & 7) * 64 + (orig >> 3);
  const int qb = wg & 15, h = (wg >> 4) & 15, b = wg >> 8;

  const u16* Qp = QK + (size_t)b * 2048 * 4096 + h * 128;
  const u16* Kp = Qp + 2048;
  const u16* Vp = VtG + (size_t)(h * 128) * 4096 + b * 2048;

  const int qrow = qb * 128 + wave * 16 + r15;
  bf16x8 qf[4];
#pragma unroll
  for (int kc = 0; kc < 4; ++kc)
    qf[kc] = *(const bf16x8*)(Qp + (size_t)qrow * 4096 + kc * 32 + g * 8);
  asm volatile("s_waitcnt vmcnt(0)" ::: "memory");

  int koff[2], voff[2];
#pragma unroll
  for (int i = 0; i < 2; ++i) {
    int c = (i * 8 + wave) * 64 + lane;        // 0..1023
    int kr = c >> 4, kj = c & 15;
    koff[i] = kr * 4096 + (kj ^ (kr & 7)) * 8;
    int vr = c >> 3, vj = c & 7;
    voff[i] = vr * 4096 + (vj ^ (vr & 7)) * 8;
  }
  const int sw = r15 & 7;

  f32x4 oacc[8] = {};
  float m = -1e30f, l = 0.f;

  // prologue: stage tile 0
#pragma unroll
  for (int i = 0; i < 2; ++i) {
    gload_lds16(Kp + koff[i], (char*)Ks[0] + (i * 8 + wave) * 1024);
    gload_lds16(Vp + voff[i], (char*)Vs[0] + (i * 8 + wave) * 1024);
  }

  for (int t = 0; t < 32; ++t) {
    const int cur = t & 1;
    if (t < 31) {
      const size_t kv0n = (size_t)(t + 1) * 64;
#pragma unroll
      for (int i = 0; i < 2; ++i) {
        gload_lds16(Kp + kv0n * 4096 + koff[i], (char*)Ks[cur ^ 1] + (i * 8 + wave) * 1024);
        gload_lds16(Vp + kv0n + voff[i], (char*)Vs[cur ^ 1] + (i * 8 + wave) * 1024);
      }
      asm volatile("s_waitcnt vmcnt(4)" ::: "memory");  // drain tile t, keep t+1 in flight
    } else {
      asm volatile("s_waitcnt vmcnt(0)" ::: "memory");
    }
    __builtin_amdgcn_s_barrier();
    __builtin_amdgcn_sched_barrier(0);

    f32x4 sacc[4] = {};
    __builtin_amdgcn_s_setprio(1);
#pragma unroll
    for (int tt = 0; tt < 4; ++tt) {
      const int krow = tt * 16 + r15;
#pragma unroll
      for (int kc = 0; kc < 4; ++kc) {
        bf16x8 kf = *(const bf16x8*)((const char*)Ks[cur] + krow * 256 +
                                     (((kc * 4 + g) ^ sw) << 4));
        sacc[tt] = __builtin_amdgcn_mfma_f32_16x16x32_bf16(kf, qf[kc], sacc[tt], 0, 0, 0);
      }
    }
    __builtin_amdgcn_s_setprio(0);

    float mx = fmaxf(fmaxf(sacc[0][0], sacc[0][1]), fmaxf(sacc[0][2], sacc[0][3]));
#pragma unroll
    for (int tt = 1; tt < 4; ++tt)
#pragma unroll
      for (int r = 0; r < 4; ++r) mx = fmaxf(mx, sacc[tt][r]);
    mx = fmaxf(mx, __shfl_xor(mx, 16));
    mx = fmaxf(mx, __shfl_xor(mx, 32));

    if (!__all(mx - m <= 8.0f)) {              // defer-max
      float mn = fmaxf(m, mx);
      float alpha = __builtin_amdgcn_exp2f(m - mn);
#pragma unroll
      for (int dt = 0; dt < 8; ++dt) oacc[dt] *= alpha;
      l *= alpha;
      m = mn;
    }

    float rs = 0.f;
    u32 pk[4][2];     // pk[tt][w] = bf16pair(kv = 16tt + 4g + 2w, +1)
#pragma unroll
    for (int tt = 0; tt < 4; ++tt)
#pragma unroll
      for (int w = 0; w < 2; ++w) {
        float p0 = __builtin_amdgcn_exp2f(sacc[tt][2 * w] - m);
        float p1 = __builtin_amdgcn_exp2f(sacc[tt][2 * w + 1] - m);
        rs += p0 + p1;
        pk[tt][w] = cvtpk_bf16(p0, p1);
      }
    rs += __shfl_xor(rs, 16);
    rs += __shfl_xor(rs, 32);
    l += rs;

    // O^T += V^T · P^T (zero-shuffle B; A uses the same k-slot placement)
    __builtin_amdgcn_s_setprio(1);
#pragma unroll
    for (int dt = 0; dt < 8; ++dt) {
      const int d = dt * 16 + r15;
      const char* vrow = (const char*)Vs[cur] + d * 128 + 8 * (g & 1);
      const int vsw = d & 7;
#pragma unroll
      for (int kh = 0; kh < 2; ++kh) {
        union { u32 u4[4]; bf16x8 v; } af, bfv;
        *(u32x2*)&af.u4[0] = *(const u32x2*)(vrow + (((kh * 4 + (g >> 1)) ^ vsw) << 4));
        *(u32x2*)&af.u4[2] = *(const u32x2*)(vrow + (((kh * 4 + 2 + (g >> 1)) ^ vsw) << 4));
        bfv.u4[0] = pk[2 * kh][0];
        bfv.u4[1] = pk[2 * kh][1];
        bfv.u4[2] = pk[2 * kh + 1][0];
        bfv.u4[3] = pk[2 * kh + 1][1];
        oacc[dt] = __builtin_amdgcn_mfma_f32_16x16x32_bf16(af.v, bfv.v, oacc[dt], 0, 0, 0);
      }
    }
    __builtin_amdgcn_s_setprio(0);

    __builtin_amdgcn_s_barrier();              // all waves done with buf[cur]
  }

  const float inv = 1.0f / l;
  u16* Ob = O + ((size_t)(b * 2048 + qrow)) * 2048 + h * 128;
#pragma unroll
  for (int dt = 0; dt < 8; ++dt) {
    u32x2 pair;
    pair[0] = cvtpk_bf16(oacc[dt][0] * inv, oacc[dt][1] * inv);
    pair[1] = cvtpk_bf16(oacc[dt][2] * inv, oacc[dt][3] * inv);
    *(u32x2*)(Ob + dt * 16 + 4 * g) = pair;
  }
}

// ---------------- host ----------------
extern "C" void kernel_launch(void* const* d_in, const int* in_sizes, int n_in,
                              void* d_out, int out_size, void* d_ws, size_t ws_size,
                              hipStream_t stream) {
  const float* x  = (const float*)d_in[0];
  const float* Wq = (const float*)d_in[1];
  const float* Wk = (const float*)d_in[2];
  const float* Wv = (const float*)d_in[3];
  const float* Wo = (const float*)d_in[4];
  const float* bo = (const float*)d_in[5];
  float* out = (float*)d_out;

  char* ws = (char*)d_ws;
  u16* xb    = (u16*)ws;                               // 16 MiB (reused as attn O)
  u16* WqkvT = (u16*)(ws + (size_t)16 * 1024 * 1024);  // 24 MiB [6144][2048]
  u16* WoT   = (u16*)(ws + (size_t)40 * 1024 * 1024);  // 8 MiB  [2048][2048]
  u16* QK    = (u16*)(ws + (size_t)48 * 1024 * 1024);  // 32 MiB [4096][4096]
  u16* VtG   = (u16*)(ws + (size_t)80 * 1024 * 1024);  // 16 MiB [2048][4096]
  u16* Oattn = xb;

  const float C2 = 0.12753102f;   // (1/sqrt(128)) * log2(e), folded into Wk

  cast_x_kernel<<<4096, 256, 0, stream>>>(x, xb);

  TC4 p;
  p.W[0] = Wq; p.W[1] = Wk; p.W[2] = Wv; p.W[3] = Wo;
  p.D[0] = WqkvT;
  p.D[1] = WqkvT + (size_t)2048 * 2048;
  p.D[2] = WqkvT + (size_t)4096 * 2048;
  p.D[3] = WoT;
  p.s[0] = 1.0f; p.s[1] = C2; p.s[2] = 1.0f; p.s[3] = 1.0f;
  transcast4<<<dim3(64, 64, 4), dim3(32, 8), 0, stream>>>(p);

  // QK = xb @ [Wq|Wk_scaled]   (M=4096, N=4096, K=2048), 256x256 tiles, 256 wgs
  gemm256<0, 256, 256, 2, 4><<<dim3(16, 16), 512, 0, stream>>>(
      xb, WqkvT, nullptr, QK, nullptr, 4096, 4096, 2048, 2048, 2048, 4096);
  // V^T = Wv^T @ x^T    (M=2048, N=4096, K=2048), 128x256 tiles, 256 wgs (was 128)
  gemm256<0, 128, 256, 2, 4><<<dim3(16, 16), 512, 0, stream>>>(
      WqkvT + (size_t)4096 * 2048, xb, nullptr, VtG, nullptr,
      2048, 4096, 2048, 2048, 2048, 4096);
  // attention: 128 q-rows per block, 512 blocks of 512 threads
  attn_kernel<<<dim3(16, 16, 2), 512, 0, stream>>>(QK, VtG, Oattn);
  // out = O @ Wo + bo   (M=4096, N=2048, K=2048), 256x128 tiles, 256 wgs (was 128)
  gemm256<1, 256, 128, 4, 2><<<dim3(16, 16), 512, 0, stream>>>(
      Oattn, WoT, out, nullptr, bo, 4096, 2048, 2048, 2048, 2048, 2048);
}